// Round 1
// baseline (4531.672 us; speedup 1.0000x reference)
//
#include <hip/hip_runtime.h>

constexpr int N   = 50000;
constexpr int E   = 500000;
constexpr int HID = 128;
constexpr int NH  = 8;
constexpr int HD  = 16;
constexpr int ED  = 32;
constexpr int EGD = 64;

__device__ __forceinline__ float gelu_f(float v) {
    return 0.5f * v * (1.f + erff(v * 0.70710678118654752f));
}
__device__ __forceinline__ float sigm_f(float v) {
    return 1.f / (1.f + __expf(-v));
}
__device__ __forceinline__ float4 f4fma(float s, float4 a, float4 c) {
    c.x += s * a.x; c.y += s * a.y; c.z += s * a.z; c.w += s * a.w;
    return c;
}

// ---------------------------------------------------------------------------
// Kernel 1: LN1 + QKV projection. 16 nodes per 256-thread block.
// ---------------------------------------------------------------------------
__global__ __launch_bounds__(256) void k_ln_qkv(
    const float* __restrict__ x, const float* __restrict__ g1, const float* __restrict__ b1,
    const float* __restrict__ Wq, const float* __restrict__ Wk, const float* __restrict__ Wv,
    float* __restrict__ Q, float* __restrict__ K, float* __restrict__ V)
{
    __shared__ float xnT[HID][16];   // [i][node-in-tile]
    const int tid = threadIdx.x;
    const int g = tid >> 4, l = tid & 15;
    const int nodeBase = blockIdx.x * 16;
    const int node = nodeBase + g;

    const float4* xp = (const float4*)(x + (size_t)node * HID + l * 8);
    float4 a0 = xp[0], a1 = xp[1];
    float xv[8] = {a0.x, a0.y, a0.z, a0.w, a1.x, a1.y, a1.z, a1.w};
    float s = 0.f, ss = 0.f;
#pragma unroll
    for (int k = 0; k < 8; k++) { s += xv[k]; ss += xv[k] * xv[k]; }
#pragma unroll
    for (int m = 1; m < 16; m <<= 1) { s += __shfl_xor(s, m); ss += __shfl_xor(ss, m); }
    float mean = s * (1.f / HID);
    float var = ss * (1.f / HID) - mean * mean;
    float ri = rsqrtf(var + 1e-5f);
#pragma unroll
    for (int k = 0; k < 8; k++) {
        int i = l * 8 + k;
        xnT[i][g] = (xv[k] - mean) * ri * g1[i] + b1[i];
    }
    __syncthreads();

    for (int c = tid; c < 384; c += 256) {
        const float* W; float* O; int cc;
        if (c < 128)      { W = Wq; O = Q; cc = c; }
        else if (c < 256) { W = Wk; O = K; cc = c - 128; }
        else              { W = Wv; O = V; cc = c - 256; }
        float4 acc0 = {0,0,0,0}, acc1 = {0,0,0,0}, acc2 = {0,0,0,0}, acc3 = {0,0,0,0};
        for (int i = 0; i < HID; i++) {
            float w = W[i * HID + cc];
            const float4* xr = (const float4*)&xnT[i][0];
            acc0 = f4fma(w, xr[0], acc0);
            acc1 = f4fma(w, xr[1], acc1);
            acc2 = f4fma(w, xr[2], acc2);
            acc3 = f4fma(w, xr[3], acc3);
        }
        float av[16] = {acc0.x, acc0.y, acc0.z, acc0.w, acc1.x, acc1.y, acc1.z, acc1.w,
                        acc2.x, acc2.y, acc2.z, acc2.w, acc3.x, acc3.y, acc3.z, acc3.w};
#pragma unroll
        for (int n = 0; n < 16; n++)
            O[(size_t)(nodeBase + n) * HID + cc] = av[n];
    }
}

// ---------------------------------------------------------------------------
// Kernel A: per-edge attention logits = QK/sqrt(D) + edge MLP; atomicMax.
// ---------------------------------------------------------------------------
__global__ __launch_bounds__(256) void k_edge_logits(
    const float* __restrict__ edge_attr, const int* __restrict__ ei,
    const float* __restrict__ Q, const float* __restrict__ K,
    const float* __restrict__ w1, const float* __restrict__ b1,
    const float* __restrict__ w2, const float* __restrict__ b2,
    float* __restrict__ logit, float* __restrict__ mbuf)
{
    int e = blockIdx.x * 256 + threadIdx.x;
    const bool valid = e < E;
    if (!valid) e = E - 1;
    const int src = ei[e], dst = ei[E + e];

    float ea[ED];
    const float4* eap = (const float4*)(edge_attr + (size_t)e * ED);
#pragma unroll
    for (int i = 0; i < ED / 4; i++) {
        float4 t = eap[i];
        ea[4*i] = t.x; ea[4*i+1] = t.y; ea[4*i+2] = t.z; ea[4*i+3] = t.w;
    }
    float4 hid[EGD / 4];
    const float4* b1v = (const float4*)b1;
#pragma unroll
    for (int t = 0; t < EGD / 4; t++) hid[t] = b1v[t];
#pragma unroll
    for (int i = 0; i < ED; i++) {
        const float4* wr = (const float4*)(w1 + i * EGD);
        float a = ea[i];
#pragma unroll
        for (int t = 0; t < EGD / 4; t++) hid[t] = f4fma(a, wr[t], hid[t]);
    }
    float hidden[EGD];
#pragma unroll
    for (int t = 0; t < EGD / 4; t++) {
        hidden[4*t+0] = gelu_f(hid[t].x); hidden[4*t+1] = gelu_f(hid[t].y);
        hidden[4*t+2] = gelu_f(hid[t].z); hidden[4*t+3] = gelu_f(hid[t].w);
    }
    float4 lgA = ((const float4*)b2)[0], lgB = ((const float4*)b2)[1];
#pragma unroll
    for (int k = 0; k < EGD; k++) {
        const float4* wp = (const float4*)(w2 + k * NH);
        lgA = f4fma(hidden[k], wp[0], lgA);
        lgB = f4fma(hidden[k], wp[1], lgB);
    }
    float lg[8] = {lgA.x, lgA.y, lgA.z, lgA.w, lgB.x, lgB.y, lgB.z, lgB.w};

    const float4* qp = (const float4*)(Q + (size_t)dst * HID);
    const float4* kp = (const float4*)(K + (size_t)src * HID);
#pragma unroll
    for (int h = 0; h < NH; h++) {
        float dot = 0.f;
#pragma unroll
        for (int t = 0; t < 4; t++) {
            float4 q = qp[h*4 + t], k4 = kp[h*4 + t];
            dot += q.x*k4.x + q.y*k4.y + q.z*k4.z + q.w*k4.w;
        }
        float lv = lg[h] + 0.25f * dot;   // D^-0.5 = 0.25
        if (valid) {
            logit[(size_t)e * NH + h] = lv;
            if (lv > 0.f)
                atomicMax((int*)(mbuf + (size_t)dst * NH + h), __float_as_int(lv));
        }
    }
}

// ---------------------------------------------------------------------------
// Kernel B: ex = exp(l - m[dst]); segment sum.
// ---------------------------------------------------------------------------
__global__ __launch_bounds__(256) void k_edge_exp(
    const int* __restrict__ ei, float* __restrict__ logit,
    const float* __restrict__ mbuf, float* __restrict__ sbuf)
{
    int i = blockIdx.x * 256 + threadIdx.x;
    if (i >= E * NH) return;
    int e = i >> 3, h = i & 7;
    int dst = ei[E + e];
    float ex = __expf(logit[i] - mbuf[dst * NH + h]);
    logit[i] = ex;
    atomicAdd(sbuf + dst * NH + h, ex);
}

// ---------------------------------------------------------------------------
// Kernel C: gate MLP + attn * gate * V[src] -> scatter-add into agg[dst].
// ---------------------------------------------------------------------------
__global__ __launch_bounds__(256) void k_edge_agg(
    const float* __restrict__ edge_attr, const int* __restrict__ ei,
    const float* __restrict__ Vb,
    const float* __restrict__ w1, const float* __restrict__ b1,
    const float* __restrict__ w2, const float* __restrict__ b2,
    const float* __restrict__ exbuf, const float* __restrict__ sbuf,
    float* __restrict__ agg)
{
    int e = blockIdx.x * 256 + threadIdx.x;
    const bool valid = e < E;
    if (!valid) e = E - 1;
    const int src = ei[e], dst = ei[E + e];

    float ea[ED];
    const float4* eap = (const float4*)(edge_attr + (size_t)e * ED);
#pragma unroll
    for (int i = 0; i < ED / 4; i++) {
        float4 t = eap[i];
        ea[4*i] = t.x; ea[4*i+1] = t.y; ea[4*i+2] = t.z; ea[4*i+3] = t.w;
    }
    float4 hid[EGD / 4];
    const float4* b1v = (const float4*)b1;
#pragma unroll
    for (int t = 0; t < EGD / 4; t++) hid[t] = b1v[t];
#pragma unroll
    for (int i = 0; i < ED; i++) {
        const float4* wr = (const float4*)(w1 + i * EGD);
        float a = ea[i];
#pragma unroll
        for (int t = 0; t < EGD / 4; t++) hid[t] = f4fma(a, wr[t], hid[t]);
    }
    float hidden[EGD];
#pragma unroll
    for (int t = 0; t < EGD / 4; t++) {
        hidden[4*t+0] = gelu_f(hid[t].x); hidden[4*t+1] = gelu_f(hid[t].y);
        hidden[4*t+2] = gelu_f(hid[t].z); hidden[4*t+3] = gelu_f(hid[t].w);
    }

    float attn[NH];
    {
        const float4* exp4 = (const float4*)(exbuf + (size_t)e * NH);
        float4 e0 = exp4[0], e1 = exp4[1];
        const float4* sp4 = (const float4*)(sbuf + (size_t)dst * NH);
        float4 s0 = sp4[0], s1 = sp4[1];
        attn[0] = e0.x / (s0.x + 1e-10f); attn[1] = e0.y / (s0.y + 1e-10f);
        attn[2] = e0.z / (s0.z + 1e-10f); attn[3] = e0.w / (s0.w + 1e-10f);
        attn[4] = e1.x / (s1.x + 1e-10f); attn[5] = e1.y / (s1.y + 1e-10f);
        attn[6] = e1.z / (s1.z + 1e-10f); attn[7] = e1.w / (s1.w + 1e-10f);
    }

    const float4* vp = (const float4*)(Vb + (size_t)src * HID);
    float* aggp = agg + (size_t)dst * HID;
#pragma unroll
    for (int h = 0; h < NH; h++) {
        float ah = attn[h];
#pragma unroll 1
        for (int q = 0; q < 4; q++) {
            int col = h * HD + q * 4;
            float4 g4 = *(const float4*)(b2 + col);
            const float* wp = w2 + col;
#pragma unroll
            for (int k = 0; k < EGD; k++) {
                float4 w = *(const float4*)(wp + k * HID);   // wave-uniform addr -> s_load
                g4 = f4fma(hidden[k], w, g4);
            }
            float4 v4 = vp[h * 4 + q];
            float rx = ah * sigm_f(g4.x) * v4.x;
            float ry = ah * sigm_f(g4.y) * v4.y;
            float rz = ah * sigm_f(g4.z) * v4.z;
            float rw = ah * sigm_f(g4.w) * v4.w;
            if (valid) {
                atomicAdd(aggp + col + 0, rx);
                atomicAdd(aggp + col + 1, ry);
                atomicAdd(aggp + col + 2, rz);
                atomicAdd(aggp + col + 3, rw);
            }
        }
    }
}

// ---------------------------------------------------------------------------
// Kernel 4: agg@Wo + bias/gamma/beta + residual + LN2 + FFN + residual.
// 16 nodes per 256-thread block.
// ---------------------------------------------------------------------------
__global__ __launch_bounds__(256) void k_node_out(
    const float* __restrict__ x, const float* __restrict__ gamma, const float* __restrict__ beta,
    const float* __restrict__ Wo, const float* __restrict__ bo,
    const float* __restrict__ g2, const float* __restrict__ b2,
    const float* __restrict__ fw1, const float* __restrict__ fb1,
    const float* __restrict__ fw2, const float* __restrict__ fb2,
    const float* __restrict__ agg, float* __restrict__ out)
{
    __shared__ float aT[HID][16];    // agg tile, later reused for x2 (normalized)
    __shared__ float x1T[HID][16];
    __shared__ float f1T[2 * HID][16];
    __shared__ float mu[16], ri[16];
    const int tid = threadIdx.x;
    const int nodeBase = blockIdx.x * 16;

    {
        int g = tid >> 4, l = tid & 15;
        const float4* ap = (const float4*)(agg + (size_t)(nodeBase + g) * HID + l * 8);
        float4 a0 = ap[0], a1 = ap[1];
        aT[l*8+0][g] = a0.x; aT[l*8+1][g] = a0.y; aT[l*8+2][g] = a0.z; aT[l*8+3][g] = a0.w;
        aT[l*8+4][g] = a1.x; aT[l*8+5][g] = a1.y; aT[l*8+6][g] = a1.z; aT[l*8+7][g] = a1.w;
    }
    __syncthreads();

    const int c = tid & 127, half = tid >> 7;
    {
        float4 acc0 = {0,0,0,0}, acc1 = {0,0,0,0};
        for (int i = 0; i < HID; i++) {
            float w = Wo[i * HID + c];
            const float4* ar = (const float4*)&aT[i][half * 8];
            acc0 = f4fma(w, ar[0], acc0);
            acc1 = f4fma(w, ar[1], acc1);
        }
        float av[8] = {acc0.x, acc0.y, acc0.z, acc0.w, acc1.x, acc1.y, acc1.z, acc1.w};
        float bc = bo[c];
#pragma unroll
        for (int n = 0; n < 8; n++) {
            int node = nodeBase + half * 8 + n;
            size_t idx = (size_t)node * HID + c;
            float o = av[n] + bc;
            float x1 = x[idx] + gamma[idx] * o + beta[idx];
            x1T[c][half * 8 + n] = x1;
        }
    }
    __syncthreads();

    {
        int g = tid >> 4, l = tid & 15;
        float s = 0.f, ss = 0.f;
#pragma unroll
        for (int k = 0; k < 8; k++) {
            float v = x1T[l + 16 * k][g];
            s += v; ss += v * v;
        }
#pragma unroll
        for (int m = 1; m < 16; m <<= 1) { s += __shfl_xor(s, m); ss += __shfl_xor(ss, m); }
        if (l == 0) {
            float mean = s * (1.f / HID);
            mu[g] = mean;
            ri[g] = rsqrtf(ss * (1.f / HID) - mean * mean + 1e-5f);
        }
    }
    __syncthreads();

    {
        int g = tid >> 4, l = tid & 15;
        float mean = mu[g], r = ri[g];
#pragma unroll
        for (int k = 0; k < 8; k++) {
            int i = l * 8 + k;
            aT[i][g] = (x1T[i][g] - mean) * r * g2[i] + b2[i];
        }
    }
    __syncthreads();

    {
        // FFN layer 1: 256 output cols, one per thread
        float4 acc0 = {0,0,0,0}, acc1 = {0,0,0,0}, acc2 = {0,0,0,0}, acc3 = {0,0,0,0};
        for (int i = 0; i < HID; i++) {
            float w = fw1[i * 256 + tid];
            const float4* ar = (const float4*)&aT[i][0];
            acc0 = f4fma(w, ar[0], acc0);
            acc1 = f4fma(w, ar[1], acc1);
            acc2 = f4fma(w, ar[2], acc2);
            acc3 = f4fma(w, ar[3], acc3);
        }
        float fb = fb1[tid];
        float av[16] = {acc0.x, acc0.y, acc0.z, acc0.w, acc1.x, acc1.y, acc1.z, acc1.w,
                        acc2.x, acc2.y, acc2.z, acc2.w, acc3.x, acc3.y, acc3.z, acc3.w};
#pragma unroll
        for (int n = 0; n < 16; n++) f1T[tid][n] = gelu_f(av[n] + fb);
    }
    __syncthreads();

    {
        float4 acc0 = {0,0,0,0}, acc1 = {0,0,0,0};
        for (int i = 0; i < 2 * HID; i++) {
            float w = fw2[i * HID + c];
            const float4* fr = (const float4*)&f1T[i][half * 8];
            acc0 = f4fma(w, fr[0], acc0);
            acc1 = f4fma(w, fr[1], acc1);
        }
        float av[8] = {acc0.x, acc0.y, acc0.z, acc0.w, acc1.x, acc1.y, acc1.z, acc1.w};
        float fb = fb2[c];
#pragma unroll
        for (int n = 0; n < 8; n++) {
            int node = nodeBase + half * 8 + n;
            out[(size_t)node * HID + c] = x1T[c][half * 8 + n] + av[n] + fb;
        }
    }
}

// ---------------------------------------------------------------------------
extern "C" void kernel_launch(void* const* d_in, const int* in_sizes, int n_in,
                              void* d_out, int out_size, void* d_ws, size_t ws_size,
                              hipStream_t stream)
{
    const float* x         = (const float*)d_in[0];
    const float* edge_attr = (const float*)d_in[1];
    const float* gamma     = (const float*)d_in[2];
    const float* beta      = (const float*)d_in[3];
    const float* Wq        = (const float*)d_in[4];
    const float* Wk        = (const float*)d_in[5];
    const float* Wv        = (const float*)d_in[6];
    const float* Wo        = (const float*)d_in[7];
    const float* bo        = (const float*)d_in[8];
    const float* ea_w1     = (const float*)d_in[9];
    const float* ea_b1     = (const float*)d_in[10];
    const float* ea_w2     = (const float*)d_in[11];
    const float* ea_b2     = (const float*)d_in[12];
    const float* eg_w1     = (const float*)d_in[13];
    const float* eg_b1     = (const float*)d_in[14];
    const float* eg_w2     = (const float*)d_in[15];
    const float* eg_b2     = (const float*)d_in[16];
    const float* ln1_g     = (const float*)d_in[17];
    const float* ln1_b     = (const float*)d_in[18];
    const float* ln2_g     = (const float*)d_in[19];
    const float* ln2_b     = (const float*)d_in[20];
    const float* fw1       = (const float*)d_in[21];
    const float* fb1       = (const float*)d_in[22];
    const float* fw2       = (const float*)d_in[23];
    const float* fb2       = (const float*)d_in[24];
    const int*   ei        = (const int*)d_in[25];

    float* ws    = (float*)d_ws;
    float* Qb    = ws;
    float* Kb    = Qb    + (size_t)N * HID;
    float* Vb    = Kb    + (size_t)N * HID;
    float* logit = Vb    + (size_t)N * HID;    // E*8, reused as ex
    float* mbuf  = logit + (size_t)E * NH;     // N*8
    float* sbuf  = mbuf  + (size_t)N * NH;     // N*8
    float* aggb  = sbuf  + (size_t)N * NH;     // N*128
    float* outp  = (float*)d_out;

    // zero mbuf, sbuf, agg (contiguous)
    hipMemsetAsync(mbuf, 0, (size_t)(N * NH * 2 + N * HID) * sizeof(float), stream);

    k_ln_qkv<<<N / 16, 256, 0, stream>>>(x, ln1_g, ln1_b, Wq, Wk, Wv, Qb, Kb, Vb);
    k_edge_logits<<<(E + 255) / 256, 256, 0, stream>>>(edge_attr, ei, Qb, Kb,
                                                       ea_w1, ea_b1, ea_w2, ea_b2,
                                                       logit, mbuf);
    k_edge_exp<<<(E * NH + 255) / 256, 256, 0, stream>>>(ei, logit, mbuf, sbuf);
    k_edge_agg<<<(E + 255) / 256, 256, 0, stream>>>(edge_attr, ei, Vb,
                                                    eg_w1, eg_b1, eg_w2, eg_b2,
                                                    logit, sbuf, aggb);
    k_node_out<<<N / 16, 256, 0, stream>>>(x, gamma, beta, Wo, bo, ln2_g, ln2_b,
                                           fw1, fb1, fw2, fb2, aggb, outp);
}

// Round 2
// 2098.637 us; speedup vs baseline: 2.1593x; 2.1593x over previous
//
#include <hip/hip_runtime.h>

constexpr int N   = 50000;
constexpr int E   = 500000;
constexpr int HID = 128;
constexpr int NH  = 8;
constexpr int HD  = 16;
constexpr int ED  = 32;
constexpr int EGD = 64;
constexpr int NB  = (N + 255) / 256;   // 196 blocks over nodes

__device__ __forceinline__ float gelu_f(float v) {
    return 0.5f * v * (1.f + erff(v * 0.70710678118654752f));
}
__device__ __forceinline__ float sigm_f(float v) {
    return 1.f / (1.f + __expf(-v));
}
__device__ __forceinline__ float4 f4fma(float s, float4 a, float4 c) {
    c.x += s * a.x; c.y += s * a.y; c.z += s * a.z; c.w += s * a.w;
    return c;
}
__device__ __forceinline__ unsigned int pack_bf16(float a, float b) {
    unsigned int ua = __float_as_uint(a);
    unsigned int ub = __float_as_uint(b);
    ua = (ua + 0x7fffu + ((ua >> 16) & 1u)) >> 16;
    ub = (ub + 0x7fffu + ((ub >> 16) & 1u)) & 0xffff0000u;
    return ua | ub;
}

// ---------------------------------------------------------------------------
// Kernel 1: LN1 + QKV projection. 16 nodes per 256-thread block.
// ---------------------------------------------------------------------------
__global__ __launch_bounds__(256) void k_ln_qkv(
    const float* __restrict__ x, const float* __restrict__ g1, const float* __restrict__ b1,
    const float* __restrict__ Wq, const float* __restrict__ Wk, const float* __restrict__ Wv,
    float* __restrict__ Q, float* __restrict__ K, float* __restrict__ V)
{
    __shared__ float xnT[HID][16];
    const int tid = threadIdx.x;
    const int g = tid >> 4, l = tid & 15;
    const int nodeBase = blockIdx.x * 16;
    const int node = nodeBase + g;

    const float4* xp = (const float4*)(x + (size_t)node * HID + l * 8);
    float4 a0 = xp[0], a1 = xp[1];
    float xv[8] = {a0.x, a0.y, a0.z, a0.w, a1.x, a1.y, a1.z, a1.w};
    float s = 0.f, ss = 0.f;
#pragma unroll
    for (int k = 0; k < 8; k++) { s += xv[k]; ss += xv[k] * xv[k]; }
#pragma unroll
    for (int m = 1; m < 16; m <<= 1) { s += __shfl_xor(s, m); ss += __shfl_xor(ss, m); }
    float mean = s * (1.f / HID);
    float var = ss * (1.f / HID) - mean * mean;
    float ri = rsqrtf(var + 1e-5f);
#pragma unroll
    for (int k = 0; k < 8; k++) {
        int i = l * 8 + k;
        xnT[i][g] = (xv[k] - mean) * ri * g1[i] + b1[i];
    }
    __syncthreads();

    for (int c = tid; c < 384; c += 256) {
        const float* W; float* O; int cc;
        if (c < 128)      { W = Wq; O = Q; cc = c; }
        else if (c < 256) { W = Wk; O = K; cc = c - 128; }
        else              { W = Wv; O = V; cc = c - 256; }
        float4 acc0 = {0,0,0,0}, acc1 = {0,0,0,0}, acc2 = {0,0,0,0}, acc3 = {0,0,0,0};
        for (int i = 0; i < HID; i++) {
            float w = W[i * HID + cc];
            const float4* xr = (const float4*)&xnT[i][0];
            acc0 = f4fma(w, xr[0], acc0);
            acc1 = f4fma(w, xr[1], acc1);
            acc2 = f4fma(w, xr[2], acc2);
            acc3 = f4fma(w, xr[3], acc3);
        }
        float av[16] = {acc0.x, acc0.y, acc0.z, acc0.w, acc1.x, acc1.y, acc1.z, acc1.w,
                        acc2.x, acc2.y, acc2.z, acc2.w, acc3.x, acc3.y, acc3.z, acc3.w};
#pragma unroll
        for (int n = 0; n < 16; n++)
            O[(size_t)(nodeBase + n) * HID + cc] = av[n];
    }
}

// ---------------------------------------------------------------------------
// Sorting: histogram -> 3-kernel exclusive scan -> scatter perm
// ---------------------------------------------------------------------------
__global__ __launch_bounds__(256) void k_hist(const int* __restrict__ ei, int* __restrict__ cnt) {
    int e = blockIdx.x * 256 + threadIdx.x;
    if (e < E) atomicAdd(&cnt[ei[E + e]], 1);
}

__global__ __launch_bounds__(256) void k_bsum(const int* __restrict__ cnt, int* __restrict__ bsum) {
    int i = blockIdx.x * 256 + threadIdx.x;
    int v = (i < N) ? cnt[i] : 0;
#pragma unroll
    for (int m = 1; m < 64; m <<= 1) v += __shfl_xor(v, m);
    __shared__ int ws4[4];
    if ((threadIdx.x & 63) == 0) ws4[threadIdx.x >> 6] = v;
    __syncthreads();
    if (threadIdx.x == 0) bsum[blockIdx.x] = ws4[0] + ws4[1] + ws4[2] + ws4[3];
}

__global__ __launch_bounds__(256) void k_scan_b(const int* __restrict__ bsum, int* __restrict__ boff) {
    __shared__ int s[256];
    int t = threadIdx.x;
    int v = (t < NB) ? bsum[t] : 0;
    s[t] = v; __syncthreads();
    for (int off = 1; off < 256; off <<= 1) {
        int add = (t >= off) ? s[t - off] : 0;
        __syncthreads();
        s[t] += add;
        __syncthreads();
    }
    if (t < NB) boff[t] = s[t] - v;
}

__global__ __launch_bounds__(256) void k_scan_final(
    const int* __restrict__ cnt, const int* __restrict__ boff,
    int* __restrict__ starts, int* __restrict__ cursor)
{
    __shared__ int s[256];
    int t = threadIdx.x, i = blockIdx.x * 256 + t;
    int v = (i < N) ? cnt[i] : 0;
    s[t] = v; __syncthreads();
    for (int off = 1; off < 256; off <<= 1) {
        int add = (t >= off) ? s[t - off] : 0;
        __syncthreads();
        s[t] += add;
        __syncthreads();
    }
    int ex = boff[blockIdx.x] + s[t] - v;
    if (i < N) {
        starts[i] = ex;
        cursor[i] = ex;
        if (i == N - 1) starts[N] = ex + v;
    }
}

__global__ __launch_bounds__(256) void k_scatter(
    const int* __restrict__ ei, int* __restrict__ cursor, int* __restrict__ perm)
{
    int e = blockIdx.x * 256 + threadIdx.x;
    if (e < E) {
        int p = atomicAdd(&cursor[ei[E + e]], 1);
        perm[p] = e;
    }
}

// ---------------------------------------------------------------------------
// Kernel A: per-edge attention logits = QK/sqrt(D) + edge MLP (no atomics).
// ---------------------------------------------------------------------------
__global__ __launch_bounds__(256) void k_edge_logits(
    const float* __restrict__ edge_attr, const int* __restrict__ ei,
    const float* __restrict__ Q, const float* __restrict__ K,
    const float* __restrict__ w1, const float* __restrict__ b1,
    const float* __restrict__ w2, const float* __restrict__ b2,
    float* __restrict__ logit)
{
    int e = blockIdx.x * 256 + threadIdx.x;
    const bool valid = e < E;
    if (!valid) e = E - 1;
    const int src = ei[e], dst = ei[E + e];

    float ea[ED];
    const float4* eap = (const float4*)(edge_attr + (size_t)e * ED);
#pragma unroll
    for (int i = 0; i < ED / 4; i++) {
        float4 t = eap[i];
        ea[4*i] = t.x; ea[4*i+1] = t.y; ea[4*i+2] = t.z; ea[4*i+3] = t.w;
    }
    float4 hid[EGD / 4];
    const float4* b1v = (const float4*)b1;
#pragma unroll
    for (int t = 0; t < EGD / 4; t++) hid[t] = b1v[t];
#pragma unroll
    for (int i = 0; i < ED; i++) {
        const float4* wr = (const float4*)(w1 + i * EGD);
        float a = ea[i];
#pragma unroll
        for (int t = 0; t < EGD / 4; t++) hid[t] = f4fma(a, wr[t], hid[t]);
    }
    float hidden[EGD];
#pragma unroll
    for (int t = 0; t < EGD / 4; t++) {
        hidden[4*t+0] = gelu_f(hid[t].x); hidden[4*t+1] = gelu_f(hid[t].y);
        hidden[4*t+2] = gelu_f(hid[t].z); hidden[4*t+3] = gelu_f(hid[t].w);
    }
    float4 lgA = ((const float4*)b2)[0], lgB = ((const float4*)b2)[1];
#pragma unroll
    for (int k = 0; k < EGD; k++) {
        const float4* wp = (const float4*)(w2 + k * NH);
        lgA = f4fma(hidden[k], wp[0], lgA);
        lgB = f4fma(hidden[k], wp[1], lgB);
    }
    float lg[8] = {lgA.x, lgA.y, lgA.z, lgA.w, lgB.x, lgB.y, lgB.z, lgB.w};

    const float4* qp = (const float4*)(Q + (size_t)dst * HID);
    const float4* kp = (const float4*)(K + (size_t)src * HID);
#pragma unroll
    for (int h = 0; h < NH; h++) {
        float dot = 0.f;
#pragma unroll
        for (int t = 0; t < 4; t++) {
            float4 q = qp[h*4 + t], k4 = kp[h*4 + t];
            dot += q.x*k4.x + q.y*k4.y + q.z*k4.z + q.w*k4.w;
        }
        if (valid) logit[(size_t)e * NH + h] = lg[h] + 0.25f * dot;
    }
}

// ---------------------------------------------------------------------------
// Segment softmax stats: one thread per (dst, h). m = max(0, segmax),
// rs = 1/(sum exp(l-m) + 1e-10).
// ---------------------------------------------------------------------------
__global__ __launch_bounds__(256) void k_softmax(
    const int* __restrict__ starts, const int* __restrict__ perm,
    const float* __restrict__ logit, float* __restrict__ marr, float* __restrict__ rsarr)
{
    int i = blockIdx.x * 256 + threadIdx.x;
    if (i >= N * NH) return;
    int dst = i >> 3, h = i & 7;
    int s0 = starts[dst], s1 = starts[dst + 1];
    float m = 0.f;
    for (int j = s0; j < s1; j++)
        m = fmaxf(m, logit[(size_t)perm[j] * NH + h]);
    float s = 0.f;
    for (int j = s0; j < s1; j++)
        s += __expf(logit[(size_t)perm[j] * NH + h] - m);
    marr[i] = m;
    rsarr[i] = 1.f / (s + 1e-10f);
}

// ---------------------------------------------------------------------------
// Kernel C: per-edge gate MLP + attn*gate*V[src] -> weighted[E][128] bf16.
// Stores staged through LDS for full-line coalescing.
// ---------------------------------------------------------------------------
__global__ __launch_bounds__(256) void k_weighted(
    const float* __restrict__ edge_attr, const int* __restrict__ ei,
    const float* __restrict__ Vb,
    const float* __restrict__ w1, const float* __restrict__ b1,
    const float* __restrict__ w2, const float* __restrict__ b2,
    const float* __restrict__ logit, const float* __restrict__ marr,
    const float* __restrict__ rsarr, unsigned int* __restrict__ wout)  // E x 64 uints
{
    __shared__ unsigned int chunkbuf[256][17];   // 17: break bank aliasing
    const int tid = threadIdx.x;
    const int eBase = blockIdx.x * 256;
    int e = eBase + tid;
    if (e >= E) e = E - 1;
    const int src = ei[e], dst = ei[E + e];

    float ea[ED];
    const float4* eap = (const float4*)(edge_attr + (size_t)e * ED);
#pragma unroll
    for (int i = 0; i < ED / 4; i++) {
        float4 t = eap[i];
        ea[4*i] = t.x; ea[4*i+1] = t.y; ea[4*i+2] = t.z; ea[4*i+3] = t.w;
    }
    float4 hid[EGD / 4];
    const float4* b1v = (const float4*)b1;
#pragma unroll
    for (int t = 0; t < EGD / 4; t++) hid[t] = b1v[t];
#pragma unroll
    for (int i = 0; i < ED; i++) {
        const float4* wr = (const float4*)(w1 + i * EGD);
        float a = ea[i];
#pragma unroll
        for (int t = 0; t < EGD / 4; t++) hid[t] = f4fma(a, wr[t], hid[t]);
    }
    float hidden[EGD];
#pragma unroll
    for (int t = 0; t < EGD / 4; t++) {
        hidden[4*t+0] = gelu_f(hid[t].x); hidden[4*t+1] = gelu_f(hid[t].y);
        hidden[4*t+2] = gelu_f(hid[t].z); hidden[4*t+3] = gelu_f(hid[t].w);
    }

#pragma unroll 1
    for (int ch = 0; ch < 4; ch++) {
        // gate for cols [ch*32, ch*32+32)
        float4 facc[8];
        const float4* b2v = (const float4*)(b2 + ch * 32);
#pragma unroll
        for (int j = 0; j < 8; j++) facc[j] = b2v[j];
#pragma unroll
        for (int k = 0; k < EGD; k++) {
            const float4* wr = (const float4*)(w2 + k * HID + ch * 32);
            float hk = hidden[k];
#pragma unroll
            for (int j = 0; j < 8; j++) facc[j] = f4fma(hk, wr[j], facc[j]);
        }
        // attention for the two heads this chunk covers
        int hA = ch * 2, hB = ch * 2 + 1;
        float aA = __expf(logit[(size_t)e * NH + hA] - marr[(size_t)dst * NH + hA])
                   * rsarr[(size_t)dst * NH + hA];
        float aB = __expf(logit[(size_t)e * NH + hB] - marr[(size_t)dst * NH + hB])
                   * rsarr[(size_t)dst * NH + hB];
        const float4* vp = (const float4*)(Vb + (size_t)src * HID + ch * 32);
        float wv[32];
#pragma unroll
        for (int j = 0; j < 8; j++) {
            float at = (j < 4) ? aA : aB;
            float4 v4 = vp[j];
            wv[4*j+0] = at * sigm_f(facc[j].x) * v4.x;
            wv[4*j+1] = at * sigm_f(facc[j].y) * v4.y;
            wv[4*j+2] = at * sigm_f(facc[j].z) * v4.z;
            wv[4*j+3] = at * sigm_f(facc[j].w) * v4.w;
        }
        __syncthreads();   // protect chunkbuf from previous iteration's readers
#pragma unroll
        for (int j = 0; j < 16; j++)
            chunkbuf[tid][j] = pack_bf16(wv[2*j], wv[2*j+1]);
        __syncthreads();
        // cooperative coalesced store: 256 edges x 16 uints for this chunk
#pragma unroll
        for (int it = 0; it < 4; it++) {
            int idx = it * 256 + tid;          // 0..1023
            int el = idx >> 2, q = idx & 3;
            if (eBase + el < E) {
                uint4 u;
                u.x = chunkbuf[el][q*4+0]; u.y = chunkbuf[el][q*4+1];
                u.z = chunkbuf[el][q*4+2]; u.w = chunkbuf[el][q*4+3];
                *(uint4*)(wout + (size_t)(eBase + el) * 64 + ch * 16 + q * 4) = u;
            }
        }
    }
}

// ---------------------------------------------------------------------------
// Kernel D: segment-sum of weighted rows. One wave per dst, float2 per lane.
// ---------------------------------------------------------------------------
__global__ __launch_bounds__(256) void k_agg(
    const int* __restrict__ starts, const int* __restrict__ perm,
    const unsigned int* __restrict__ wv, float* __restrict__ agg)
{
    int wave = threadIdx.x >> 6, lane = threadIdx.x & 63;
    int dst = blockIdx.x * 4 + wave;
    if (dst >= N) return;
    int s0 = starts[dst], s1 = starts[dst + 1];
    float ax = 0.f, ay = 0.f;
    for (int j = s0; j < s1; j++) {
        int e = perm[j];
        unsigned int u = wv[(size_t)e * 64 + lane];
        ax += __uint_as_float(u << 16);
        ay += __uint_as_float(u & 0xffff0000u);
    }
    float2* o = (float2*)(agg + (size_t)dst * HID + lane * 2);
    *o = make_float2(ax, ay);
}

// ---------------------------------------------------------------------------
// Kernel 4: agg@Wo + gamma/beta + residual + LN2 + FFN + residual.
// ---------------------------------------------------------------------------
__global__ __launch_bounds__(256) void k_node_out(
    const float* __restrict__ x, const float* __restrict__ gamma, const float* __restrict__ beta,
    const float* __restrict__ Wo, const float* __restrict__ bo,
    const float* __restrict__ g2, const float* __restrict__ b2,
    const float* __restrict__ fw1, const float* __restrict__ fb1,
    const float* __restrict__ fw2, const float* __restrict__ fb2,
    const float* __restrict__ agg, float* __restrict__ out)
{
    __shared__ float aT[HID][16];
    __shared__ float x1T[HID][16];
    __shared__ float f1T[2 * HID][16];
    __shared__ float mu[16], ri[16];
    const int tid = threadIdx.x;
    const int nodeBase = blockIdx.x * 16;

    {
        int g = tid >> 4, l = tid & 15;
        const float4* ap = (const float4*)(agg + (size_t)(nodeBase + g) * HID + l * 8);
        float4 a0 = ap[0], a1 = ap[1];
        aT[l*8+0][g] = a0.x; aT[l*8+1][g] = a0.y; aT[l*8+2][g] = a0.z; aT[l*8+3][g] = a0.w;
        aT[l*8+4][g] = a1.x; aT[l*8+5][g] = a1.y; aT[l*8+6][g] = a1.z; aT[l*8+7][g] = a1.w;
    }
    __syncthreads();

    const int c = tid & 127, half = tid >> 7;
    {
        float4 acc0 = {0,0,0,0}, acc1 = {0,0,0,0};
        for (int i = 0; i < HID; i++) {
            float w = Wo[i * HID + c];
            const float4* ar = (const float4*)&aT[i][half * 8];
            acc0 = f4fma(w, ar[0], acc0);
            acc1 = f4fma(w, ar[1], acc1);
        }
        float av[8] = {acc0.x, acc0.y, acc0.z, acc0.w, acc1.x, acc1.y, acc1.z, acc1.w};
        float bc = bo[c];
#pragma unroll
        for (int n = 0; n < 8; n++) {
            int node = nodeBase + half * 8 + n;
            size_t idx = (size_t)node * HID + c;
            float o = av[n] + bc;
            x1T[c][half * 8 + n] = x[idx] + gamma[idx] * o + beta[idx];
        }
    }
    __syncthreads();

    {
        int g = tid >> 4, l = tid & 15;
        float s = 0.f, ss = 0.f;
#pragma unroll
        for (int k = 0; k < 8; k++) {
            float v = x1T[l + 16 * k][g];
            s += v; ss += v * v;
        }
#pragma unroll
        for (int m = 1; m < 16; m <<= 1) { s += __shfl_xor(s, m); ss += __shfl_xor(ss, m); }
        if (l == 0) {
            float mean = s * (1.f / HID);
            mu[g] = mean;
            ri[g] = rsqrtf(ss * (1.f / HID) - mean * mean + 1e-5f);
        }
    }
    __syncthreads();

    {
        int g = tid >> 4, l = tid & 15;
        float mean = mu[g], r = ri[g];
#pragma unroll
        for (int k = 0; k < 8; k++) {
            int i = l * 8 + k;
            aT[i][g] = (x1T[i][g] - mean) * r * g2[i] + b2[i];
        }
    }
    __syncthreads();

    {
        float4 acc0 = {0,0,0,0}, acc1 = {0,0,0,0}, acc2 = {0,0,0,0}, acc3 = {0,0,0,0};
        for (int i = 0; i < HID; i++) {
            float w = fw1[i * 256 + tid];
            const float4* ar = (const float4*)&aT[i][0];
            acc0 = f4fma(w, ar[0], acc0);
            acc1 = f4fma(w, ar[1], acc1);
            acc2 = f4fma(w, ar[2], acc2);
            acc3 = f4fma(w, ar[3], acc3);
        }
        float fb = fb1[tid];
        float av[16] = {acc0.x, acc0.y, acc0.z, acc0.w, acc1.x, acc1.y, acc1.z, acc1.w,
                        acc2.x, acc2.y, acc2.z, acc2.w, acc3.x, acc3.y, acc3.z, acc3.w};
#pragma unroll
        for (int n = 0; n < 16; n++) f1T[tid][n] = gelu_f(av[n] + fb);
    }
    __syncthreads();

    {
        float4 acc0 = {0,0,0,0}, acc1 = {0,0,0,0};
        for (int i = 0; i < 2 * HID; i++) {
            float w = fw2[i * HID + c];
            const float4* fr = (const float4*)&f1T[i][half * 8];
            acc0 = f4fma(w, fr[0], acc0);
            acc1 = f4fma(w, fr[1], acc1);
        }
        float av[8] = {acc0.x, acc0.y, acc0.z, acc0.w, acc1.x, acc1.y, acc1.z, acc1.w};
        float fb = fb2[c];
#pragma unroll
        for (int n = 0; n < 8; n++) {
            int node = nodeBase + half * 8 + n;
            out[(size_t)node * HID + c] = x1T[c][half * 8 + n] + av[n] + fb;
        }
    }
}

// ---------------------------------------------------------------------------
extern "C" void kernel_launch(void* const* d_in, const int* in_sizes, int n_in,
                              void* d_out, int out_size, void* d_ws, size_t ws_size,
                              hipStream_t stream)
{
    const float* x         = (const float*)d_in[0];
    const float* edge_attr = (const float*)d_in[1];
    const float* gamma     = (const float*)d_in[2];
    const float* beta      = (const float*)d_in[3];
    const float* Wq        = (const float*)d_in[4];
    const float* Wk        = (const float*)d_in[5];
    const float* Wv        = (const float*)d_in[6];
    const float* Wo        = (const float*)d_in[7];
    const float* bo        = (const float*)d_in[8];
    const float* ea_w1     = (const float*)d_in[9];
    const float* ea_b1     = (const float*)d_in[10];
    const float* ea_w2     = (const float*)d_in[11];
    const float* ea_b2     = (const float*)d_in[12];
    const float* eg_w1     = (const float*)d_in[13];
    const float* eg_b1     = (const float*)d_in[14];
    const float* eg_w2     = (const float*)d_in[15];
    const float* eg_b2     = (const float*)d_in[16];
    const float* ln1_g     = (const float*)d_in[17];
    const float* ln1_b     = (const float*)d_in[18];
    const float* ln2_g     = (const float*)d_in[19];
    const float* ln2_b     = (const float*)d_in[20];
    const float* fw1       = (const float*)d_in[21];
    const float* fb1       = (const float*)d_in[22];
    const float* fw2       = (const float*)d_in[23];
    const float* fb2       = (const float*)d_in[24];
    const int*   ei        = (const int*)d_in[25];

    char* wsb = (char*)d_ws;
    size_t off = 0;
    auto alloc = [&](size_t bytes) { void* p = wsb + off; off += (bytes + 255) & ~(size_t)255; return p; };

    float* Qb     = (float*)alloc((size_t)N * HID * 4);
    float* Kb     = (float*)alloc((size_t)N * HID * 4);
    float* Vb     = (float*)alloc((size_t)N * HID * 4);
    float* logit  = (float*)alloc((size_t)E * NH * 4);
    float* marr   = (float*)alloc((size_t)N * NH * 4);
    float* rsarr  = (float*)alloc((size_t)N * NH * 4);
    float* aggb   = (float*)alloc((size_t)N * HID * 4);
    int*   cnt    = (int*)alloc((size_t)N * 4);
    int*   starts = (int*)alloc((size_t)(N + 1) * 4);
    int*   cursor = (int*)alloc((size_t)N * 4);
    int*   bsum   = (int*)alloc((size_t)NB * 4);
    int*   boff   = (int*)alloc((size_t)NB * 4);
    int*   perm   = (int*)alloc((size_t)E * 4);
    unsigned int* wvb = (unsigned int*)alloc((size_t)E * 64 * 4);  // bf16 x2 packed
    float* outp   = (float*)d_out;

    hipMemsetAsync(cnt, 0, (size_t)N * sizeof(int), stream);

    const int EB = (E + 255) / 256;
    k_ln_qkv<<<N / 16, 256, 0, stream>>>(x, ln1_g, ln1_b, Wq, Wk, Wv, Qb, Kb, Vb);
    k_hist<<<EB, 256, 0, stream>>>(ei, cnt);
    k_bsum<<<NB, 256, 0, stream>>>(cnt, bsum);
    k_scan_b<<<1, 256, 0, stream>>>(bsum, boff);
    k_scan_final<<<NB, 256, 0, stream>>>(cnt, boff, starts, cursor);
    k_scatter<<<EB, 256, 0, stream>>>(ei, cursor, perm);
    k_edge_logits<<<EB, 256, 0, stream>>>(edge_attr, ei, Qb, Kb,
                                          ea_w1, ea_b1, ea_w2, ea_b2, logit);
    k_softmax<<<(N * NH + 255) / 256, 256, 0, stream>>>(starts, perm, logit, marr, rsarr);
    k_weighted<<<EB, 256, 0, stream>>>(edge_attr, ei, Vb,
                                       eg_w1, eg_b1, eg_w2, eg_b2,
                                       logit, marr, rsarr, wvb);
    k_agg<<<(N + 3) / 4, 256, 0, stream>>>(starts, perm, wvb, aggb);
    k_node_out<<<N / 16, 256, 0, stream>>>(x, gamma, beta, Wo, bo, ln2_g, ln2_b,
                                           fw1, fb1, fw2, fb2, aggb, outp);
}

// Round 3
// 861.579 us; speedup vs baseline: 5.2597x; 2.4358x over previous
//
#include <hip/hip_runtime.h>

constexpr int N   = 50000;
constexpr int E   = 500000;
constexpr int HID = 128;
constexpr int NH  = 8;
constexpr int ED  = 32;
constexpr int EGD = 64;
constexpr int NB  = (N + 255) / 256;

typedef short  bf16x8 __attribute__((ext_vector_type(8)));
typedef float  f32x4  __attribute__((ext_vector_type(4)));

__device__ __forceinline__ float gelu_f(float v) {
    return 0.5f * v * (1.f + erff(v * 0.70710678118654752f));
}
__device__ __forceinline__ float sigm_f(float v) {
    return 1.f / (1.f + __expf(-v));
}
__device__ __forceinline__ float4 f4fma(float s, float4 a, float4 c) {
    c.x += s * a.x; c.y += s * a.y; c.z += s * a.z; c.w += s * a.w;
    return c;
}
__device__ __forceinline__ unsigned short f2bf(float f) {
    unsigned int u = __float_as_uint(f);
    return (unsigned short)((u + 0x7fffu + ((u >> 16) & 1u)) >> 16);
}

// ---------------------------------------------------------------------------
// Weight conversion to bf16 (ea_w2 zero-padded 64x8 -> 64x16)
// ---------------------------------------------------------------------------
__global__ __launch_bounds__(256) void k_cvt_w(
    const float* __restrict__ ea_w1, const float* __restrict__ ea_w2,
    const float* __restrict__ eg_w1, const float* __restrict__ eg_w2,
    unsigned short* __restrict__ w1ea, unsigned short* __restrict__ w2ea,
    unsigned short* __restrict__ w1eg, unsigned short* __restrict__ w2eg)
{
    int t = blockIdx.x * 256 + threadIdx.x;
    if (t < 2048) w1ea[t] = f2bf(ea_w1[t]);
    if (t < 1024) {
        int k = t >> 4, n = t & 15;
        w2ea[t] = (n < 8) ? f2bf(ea_w2[k * 8 + n]) : (unsigned short)0;
    }
    if (t < 2048) w1eg[t] = f2bf(eg_w1[t]);
    if (t < 8192) w2eg[t] = f2bf(eg_w2[t]);
}

// ---------------------------------------------------------------------------
// Kernel 1: LN1 + QKV projection. 16 nodes per 256-thread block.
// ---------------------------------------------------------------------------
__global__ __launch_bounds__(256) void k_ln_qkv(
    const float* __restrict__ x, const float* __restrict__ g1, const float* __restrict__ b1,
    const float* __restrict__ Wq, const float* __restrict__ Wk, const float* __restrict__ Wv,
    float* __restrict__ Q, float* __restrict__ K, float* __restrict__ V)
{
    __shared__ float xnT[HID][16];
    const int tid = threadIdx.x;
    const int g = tid >> 4, l = tid & 15;
    const int nodeBase = blockIdx.x * 16;
    const int node = nodeBase + g;

    const float4* xp = (const float4*)(x + (size_t)node * HID + l * 8);
    float4 a0 = xp[0], a1 = xp[1];
    float xv[8] = {a0.x, a0.y, a0.z, a0.w, a1.x, a1.y, a1.z, a1.w};
    float s = 0.f, ss = 0.f;
#pragma unroll
    for (int k = 0; k < 8; k++) { s += xv[k]; ss += xv[k] * xv[k]; }
#pragma unroll
    for (int m = 1; m < 16; m <<= 1) { s += __shfl_xor(s, m); ss += __shfl_xor(ss, m); }
    float mean = s * (1.f / HID);
    float var = ss * (1.f / HID) - mean * mean;
    float ri = rsqrtf(var + 1e-5f);
#pragma unroll
    for (int k = 0; k < 8; k++) {
        int i = l * 8 + k;
        xnT[i][g] = (xv[k] - mean) * ri * g1[i] + b1[i];
    }
    __syncthreads();

    for (int c = tid; c < 384; c += 256) {
        const float* W; float* O; int cc;
        if (c < 128)      { W = Wq; O = Q; cc = c; }
        else if (c < 256) { W = Wk; O = K; cc = c - 128; }
        else              { W = Wv; O = V; cc = c - 256; }
        float4 acc0 = {0,0,0,0}, acc1 = {0,0,0,0}, acc2 = {0,0,0,0}, acc3 = {0,0,0,0};
        for (int i = 0; i < HID; i++) {
            float w = W[i * HID + cc];
            const float4* xr = (const float4*)&xnT[i][0];
            acc0 = f4fma(w, xr[0], acc0);
            acc1 = f4fma(w, xr[1], acc1);
            acc2 = f4fma(w, xr[2], acc2);
            acc3 = f4fma(w, xr[3], acc3);
        }
        float av[16] = {acc0.x, acc0.y, acc0.z, acc0.w, acc1.x, acc1.y, acc1.z, acc1.w,
                        acc2.x, acc2.y, acc2.z, acc2.w, acc3.x, acc3.y, acc3.z, acc3.w};
#pragma unroll
        for (int n = 0; n < 16; n++)
            O[(size_t)(nodeBase + n) * HID + cc] = av[n];
    }
}

// ---------------------------------------------------------------------------
// Sorting: histogram -> scan -> scatter perm
// ---------------------------------------------------------------------------
__global__ __launch_bounds__(256) void k_hist(const int* __restrict__ ei, int* __restrict__ cnt) {
    int e = blockIdx.x * 256 + threadIdx.x;
    if (e < E) atomicAdd(&cnt[ei[E + e]], 1);
}

__global__ __launch_bounds__(256) void k_bsum(const int* __restrict__ cnt, int* __restrict__ bsum) {
    int i = blockIdx.x * 256 + threadIdx.x;
    int v = (i < N) ? cnt[i] : 0;
#pragma unroll
    for (int m = 1; m < 64; m <<= 1) v += __shfl_xor(v, m);
    __shared__ int ws4[4];
    if ((threadIdx.x & 63) == 0) ws4[threadIdx.x >> 6] = v;
    __syncthreads();
    if (threadIdx.x == 0) bsum[blockIdx.x] = ws4[0] + ws4[1] + ws4[2] + ws4[3];
}

__global__ __launch_bounds__(256) void k_scan_b(const int* __restrict__ bsum, int* __restrict__ boff) {
    __shared__ int s[256];
    int t = threadIdx.x;
    int v = (t < NB) ? bsum[t] : 0;
    s[t] = v; __syncthreads();
    for (int off = 1; off < 256; off <<= 1) {
        int add = (t >= off) ? s[t - off] : 0;
        __syncthreads();
        s[t] += add;
        __syncthreads();
    }
    if (t < NB) boff[t] = s[t] - v;
}

__global__ __launch_bounds__(256) void k_scan_final(
    const int* __restrict__ cnt, const int* __restrict__ boff,
    int* __restrict__ starts, int* __restrict__ cursor)
{
    __shared__ int s[256];
    int t = threadIdx.x, i = blockIdx.x * 256 + t;
    int v = (i < N) ? cnt[i] : 0;
    s[t] = v; __syncthreads();
    for (int off = 1; off < 256; off <<= 1) {
        int add = (t >= off) ? s[t - off] : 0;
        __syncthreads();
        s[t] += add;
        __syncthreads();
    }
    int ex = boff[blockIdx.x] + s[t] - v;
    if (i < N) {
        starts[i] = ex;
        cursor[i] = ex;
        if (i == N - 1) starts[N] = ex + v;
    }
}

__global__ __launch_bounds__(256) void k_scatter(
    const int* __restrict__ ei, int* __restrict__ cursor, int* __restrict__ perm)
{
    int e = blockIdx.x * 256 + threadIdx.x;
    if (e < E) {
        int p = atomicAdd(&cursor[ei[E + e]], 1);
        perm[p] = e;
    }
}

// ---------------------------------------------------------------------------
// MFMA edge-MLP logits: gelu(ea@w1+b1)@w2 + b2 + 0.25*QK -> logit[E][8]
// Block = 256 edges, 4 waves x 64 edges.
// ---------------------------------------------------------------------------
__global__ __launch_bounds__(256) void k_logits_mfma(
    const float* __restrict__ edge_attr, const int* __restrict__ ei,
    const float* __restrict__ Q, const float* __restrict__ K,
    const unsigned short* __restrict__ w1b, const float* __restrict__ b1,
    const unsigned short* __restrict__ w2b, const float* __restrict__ b2,
    float* __restrict__ logit)
{
    __shared__ unsigned short ea_lds[256 * 32];   // bf16, xor-swizzled granules of 8
    __shared__ unsigned short hid_lds[256 * 64];  // bf16, xor-swizzled granules of 8
    __shared__ float st8[256 * 8];

    const int tid = threadIdx.x;
    const int eBase = blockIdx.x * 256;
    const int lane = tid & 63;
    const int wv = tid >> 6;
    const int wBase = wv * 64;
    const int lm = lane & 15;
    const int kb = lane >> 4;
    const int rowq = kb * 4;

    // stage edge_attr -> bf16 LDS (swizzled)
#pragma unroll
    for (int it = 0; it < 8; it++) {
        int idx = it * 256 + tid;
        int e = idx >> 3, c = (idx & 7) * 4;
        int ge = eBase + e; if (ge >= E) ge = E - 1;
        float4 v = *(const float4*)(edge_attr + (size_t)ge * ED + c);
        int g = ((c >> 3) ^ (e & 3));
        unsigned short* p = &ea_lds[e * 32 + g * 8 + (c & 7)];
        p[0] = f2bf(v.x); p[1] = f2bf(v.y); p[2] = f2bf(v.z); p[3] = f2bf(v.w);
    }
    __syncthreads();

    // GEMM1: hidden = gelu(ea @ w1 + b1)
    bf16x8 a1[4];
#pragma unroll
    for (int mt = 0; mt < 4; mt++) {
        int m = wBase + mt * 16 + lm;
        a1[mt] = *(const bf16x8*)&ea_lds[m * 32 + (kb ^ (m & 3)) * 8];
    }
    f32x4 acc1[4][4];
    {
        bf16x8 bfr[4];
#pragma unroll
        for (int nt = 0; nt < 4; nt++) {
            union { bf16x8 v; unsigned short u[8]; } t;
#pragma unroll
            for (int j = 0; j < 8; j++)
                t.u[j] = w1b[(kb * 8 + j) * EGD + nt * 16 + lm];
            bfr[nt] = t.v;
        }
#pragma unroll
        for (int mt = 0; mt < 4; mt++)
#pragma unroll
            for (int nt = 0; nt < 4; nt++) {
                f32x4 z = {0.f, 0.f, 0.f, 0.f};
                acc1[mt][nt] = __builtin_amdgcn_mfma_f32_16x16x32_bf16(a1[mt], bfr[nt], z, 0, 0, 0);
            }
    }
#pragma unroll
    for (int nt = 0; nt < 4; nt++) {
        float bias = b1[nt * 16 + lm];
#pragma unroll
        for (int mt = 0; mt < 4; mt++)
#pragma unroll
            for (int r = 0; r < 4; r++) {
                int row = wBase + mt * 16 + rowq + r;
                int col = nt * 16 + lm;
                int g = (col >> 3) ^ (row & 7);
                hid_lds[row * 64 + g * 8 + (col & 7)] = f2bf(gelu_f(acc1[mt][nt][r] + bias));
            }
    }

    // GEMM2: mlp_logit = hidden @ w2 (64x16, cols 8..15 zero) + b2
    bf16x8 a2[4][2];
#pragma unroll
    for (int mt = 0; mt < 4; mt++)
#pragma unroll
        for (int ks = 0; ks < 2; ks++) {
            int m = wBase + mt * 16 + lm;
            int g = (ks * 4 + kb) ^ (m & 7);
            a2[mt][ks] = *(const bf16x8*)&hid_lds[m * 64 + g * 8];
        }
    {
        bf16x8 bfr[2];
#pragma unroll
        for (int ks = 0; ks < 2; ks++) {
            union { bf16x8 v; unsigned short u[8]; } t;
#pragma unroll
            for (int j = 0; j < 8; j++)
                t.u[j] = w2b[(ks * 32 + kb * 8 + j) * 16 + lm];
            bfr[ks] = t.v;
        }
        float bias = b2[lm & 7];
#pragma unroll
        for (int mt = 0; mt < 4; mt++) {
            f32x4 acc = {bias, bias, bias, bias};
            acc = __builtin_amdgcn_mfma_f32_16x16x32_bf16(a2[mt][0], bfr[0], acc, 0, 0, 0);
            acc = __builtin_amdgcn_mfma_f32_16x16x32_bf16(a2[mt][1], bfr[1], acc, 0, 0, 0);
            if (lm < 8) {
#pragma unroll
                for (int r = 0; r < 4; r++)
                    st8[(wBase + mt * 16 + rowq + r) * 8 + lm] = acc[r];
            }
        }
    }
    __syncthreads();

    // per-thread epilogue: += 0.25 * Q[dst].K[src] per head, store
    int e = eBase + tid;
    if (e < E) {
        int src = ei[e], dst = ei[E + e];
        const float4* qp = (const float4*)(Q + (size_t)dst * HID);
        const float4* kp = (const float4*)(K + (size_t)src * HID);
        float lg[8];
#pragma unroll
        for (int h = 0; h < 8; h++) {
            float dot = 0.f;
#pragma unroll
            for (int t = 0; t < 4; t++) {
                float4 q = qp[h * 4 + t], k4 = kp[h * 4 + t];
                dot += q.x * k4.x + q.y * k4.y + q.z * k4.z + q.w * k4.w;
            }
            lg[h] = st8[tid * 8 + h] + 0.25f * dot;
        }
        float4* op = (float4*)(logit + (size_t)e * NH);
        op[0] = make_float4(lg[0], lg[1], lg[2], lg[3]);
        op[1] = make_float4(lg[4], lg[5], lg[6], lg[7]);
    }
}

// ---------------------------------------------------------------------------
// Segment softmax stats: one thread per (dst, h).
// ---------------------------------------------------------------------------
__global__ __launch_bounds__(256) void k_softmax(
    const int* __restrict__ starts, const int* __restrict__ perm,
    const float* __restrict__ logit, float* __restrict__ marr, float* __restrict__ rsarr)
{
    int i = blockIdx.x * 256 + threadIdx.x;
    if (i >= N * NH) return;
    int dst = i >> 3, h = i & 7;
    int s0 = starts[dst], s1 = starts[dst + 1];
    float m = 0.f;
    for (int j = s0; j < s1; j++)
        m = fmaxf(m, logit[(size_t)perm[j] * NH + h]);
    float s = 0.f;
    for (int j = s0; j < s1; j++)
        s += __expf(logit[(size_t)perm[j] * NH + h] - m);
    marr[i] = m;
    rsarr[i] = 1.f / (s + 1e-10f);
}

// ---------------------------------------------------------------------------
// MFMA gate MLP + attn*sigmoid(gate)*V[src] -> weighted[E][128] bf16.
// ---------------------------------------------------------------------------
__global__ __launch_bounds__(256) void k_weighted_mfma(
    const float* __restrict__ edge_attr, const int* __restrict__ ei,
    const float* __restrict__ Vb,
    const unsigned short* __restrict__ w1b, const float* __restrict__ b1,
    const unsigned short* __restrict__ w2b, const float* __restrict__ b2,
    const float* __restrict__ logit, const float* __restrict__ marr,
    const float* __restrict__ rsarr, unsigned int* __restrict__ wout)
{
    __shared__ unsigned short ea_lds[256 * 32];   // bf16 swizzled; reused as store stage
    __shared__ unsigned short hid_lds[256 * 64];  // bf16 swizzled
    __shared__ float attn_lds[256 * 8];
    __shared__ int src_lds[256];

    const int tid = threadIdx.x;
    const int eBase = blockIdx.x * 256;
    const int lane = tid & 63;
    const int wv = tid >> 6;
    const int wBase = wv * 64;
    const int lm = lane & 15;
    const int kb = lane >> 4;
    const int rowq = kb * 4;

    // stage edge_attr
#pragma unroll
    for (int it = 0; it < 8; it++) {
        int idx = it * 256 + tid;
        int e = idx >> 3, c = (idx & 7) * 4;
        int ge = eBase + e; if (ge >= E) ge = E - 1;
        float4 v = *(const float4*)(edge_attr + (size_t)ge * ED + c);
        int g = ((c >> 3) ^ (e & 3));
        unsigned short* p = &ea_lds[e * 32 + g * 8 + (c & 7)];
        p[0] = f2bf(v.x); p[1] = f2bf(v.y); p[2] = f2bf(v.z); p[3] = f2bf(v.w);
    }
    // attn + src
    {
        int e = eBase + tid; if (e >= E) e = E - 1;
        int src = ei[e], dst = ei[E + e];
        src_lds[tid] = src;
        const float4* lp = (const float4*)(logit + (size_t)e * NH);
        const float4* mp = (const float4*)(marr + (size_t)dst * NH);
        const float4* rp = (const float4*)(rsarr + (size_t)dst * NH);
#pragma unroll
        for (int q = 0; q < 2; q++) {
            float4 l4 = lp[q], m4 = mp[q], r4 = rp[q];
            float4 a4;
            a4.x = __expf(l4.x - m4.x) * r4.x;
            a4.y = __expf(l4.y - m4.y) * r4.y;
            a4.z = __expf(l4.z - m4.z) * r4.z;
            a4.w = __expf(l4.w - m4.w) * r4.w;
            *(float4*)&attn_lds[tid * 8 + q * 4] = a4;
        }
    }
    __syncthreads();

    // GEMM1
    bf16x8 a1[4];
#pragma unroll
    for (int mt = 0; mt < 4; mt++) {
        int m = wBase + mt * 16 + lm;
        a1[mt] = *(const bf16x8*)&ea_lds[m * 32 + (kb ^ (m & 3)) * 8];
    }
    f32x4 acc1[4][4];
    {
        bf16x8 bfr[4];
#pragma unroll
        for (int nt = 0; nt < 4; nt++) {
            union { bf16x8 v; unsigned short u[8]; } t;
#pragma unroll
            for (int j = 0; j < 8; j++)
                t.u[j] = w1b[(kb * 8 + j) * EGD + nt * 16 + lm];
            bfr[nt] = t.v;
        }
#pragma unroll
        for (int mt = 0; mt < 4; mt++)
#pragma unroll
            for (int nt = 0; nt < 4; nt++) {
                f32x4 z = {0.f, 0.f, 0.f, 0.f};
                acc1[mt][nt] = __builtin_amdgcn_mfma_f32_16x16x32_bf16(a1[mt], bfr[nt], z, 0, 0, 0);
            }
    }
#pragma unroll
    for (int nt = 0; nt < 4; nt++) {
        float bias = b1[nt * 16 + lm];
#pragma unroll
        for (int mt = 0; mt < 4; mt++)
#pragma unroll
            for (int r = 0; r < 4; r++) {
                int row = wBase + mt * 16 + rowq + r;
                int col = nt * 16 + lm;
                int g = (col >> 3) ^ (row & 7);
                hid_lds[row * 64 + g * 8 + (col & 7)] = f2bf(gelu_f(acc1[mt][nt][r] + bias));
            }
    }

    // GEMM2 A-fragments
    bf16x8 a2[4][2];
#pragma unroll
    for (int mt = 0; mt < 4; mt++)
#pragma unroll
        for (int ks = 0; ks < 2; ks++) {
            int m = wBase + mt * 16 + lm;
            int g = (ks * 4 + kb) ^ (m & 7);
            a2[mt][ks] = *(const bf16x8*)&hid_lds[m * 64 + g * 8];
        }

    // 4 chunks of 32 cols
#pragma unroll 1
    for (int ch = 0; ch < 4; ch++) {
        const int cc = ch * 32;
        bf16x8 b2f[2][2];
#pragma unroll
        for (int nt = 0; nt < 2; nt++)
#pragma unroll
            for (int ks = 0; ks < 2; ks++) {
                union { bf16x8 v; unsigned short u[8]; } t;
#pragma unroll
                for (int j = 0; j < 8; j++)
                    t.u[j] = w2b[(ks * 32 + kb * 8 + j) * HID + cc + nt * 16 + lm];
                b2f[nt][ks] = t.v;
            }
        f32x4 acc[4][2];
#pragma unroll
        for (int nt = 0; nt < 2; nt++) {
            float bias = b2[cc + nt * 16 + lm];
#pragma unroll
            for (int mt = 0; mt < 4; mt++) {
                f32x4 c = {bias, bias, bias, bias};
                c = __builtin_amdgcn_mfma_f32_16x16x32_bf16(a2[mt][0], b2f[nt][0], c, 0, 0, 0);
                c = __builtin_amdgcn_mfma_f32_16x16x32_bf16(a2[mt][1], b2f[nt][1], c, 0, 0, 0);
                acc[mt][nt] = c;
            }
        }
        __syncthreads();   // previous chunk's cooperative reads of ea_lds done
#pragma unroll
        for (int nt = 0; nt < 2; nt++) {
            int head = ch * 2 + nt;
#pragma unroll
            for (int mt = 0; mt < 4; mt++)
#pragma unroll
                for (int r = 0; r < 4; r++) {
                    int em = wBase + mt * 16 + rowq + r;
                    float a = attn_lds[em * 8 + head];
                    int src = src_lds[em];
                    float vval = Vb[(size_t)src * HID + cc + nt * 16 + lm];
                    float w = a * sigm_f(acc[mt][nt][r]) * vval;
                    int cl = nt * 16 + lm;
                    int g = (cl >> 3) ^ (em & 3);
                    ea_lds[em * 32 + g * 8 + (cl & 7)] = f2bf(w);
                }
        }
        __syncthreads();
#pragma unroll
        for (int it = 0; it < 4; it++) {
            int idx = it * 256 + tid;
            int el = idx >> 2, q = idx & 3;
            if (eBase + el < E) {
                int g = q ^ (el & 3);
                uint4 u = *(const uint4*)&ea_lds[el * 32 + g * 8];
                *(uint4*)(wout + (size_t)(eBase + el) * 64 + ch * 16 + q * 4) = u;
            }
        }
    }
}

// ---------------------------------------------------------------------------
// Kernel D: segment-sum of weighted rows. One wave per dst.
// ---------------------------------------------------------------------------
__global__ __launch_bounds__(256) void k_agg(
    const int* __restrict__ starts, const int* __restrict__ perm,
    const unsigned int* __restrict__ wv, float* __restrict__ agg)
{
    int wave = threadIdx.x >> 6, lane = threadIdx.x & 63;
    int dst = blockIdx.x * 4 + wave;
    if (dst >= N) return;
    int s0 = starts[dst], s1 = starts[dst + 1];
    float ax = 0.f, ay = 0.f;
    for (int j = s0; j < s1; j++) {
        int e = perm[j];
        unsigned int u = wv[(size_t)e * 64 + lane];
        ax += __uint_as_float(u << 16);
        ay += __uint_as_float(u & 0xffff0000u);
    }
    float2* o = (float2*)(agg + (size_t)dst * HID + lane * 2);
    *o = make_float2(ax, ay);
}

// ---------------------------------------------------------------------------
// Kernel 4: agg@Wo + gamma/beta + residual + LN2 + FFN + residual.
// ---------------------------------------------------------------------------
__global__ __launch_bounds__(256) void k_node_out(
    const float* __restrict__ x, const float* __restrict__ gamma, const float* __restrict__ beta,
    const float* __restrict__ Wo, const float* __restrict__ bo,
    const float* __restrict__ g2, const float* __restrict__ b2,
    const float* __restrict__ fw1, const float* __restrict__ fb1,
    const float* __restrict__ fw2, const float* __restrict__ fb2,
    const float* __restrict__ agg, float* __restrict__ out)
{
    __shared__ float aT[HID][16];
    __shared__ float x1T[HID][16];
    __shared__ float f1T[2 * HID][16];
    __shared__ float mu[16], ri[16];
    const int tid = threadIdx.x;
    const int nodeBase = blockIdx.x * 16;

    {
        int g = tid >> 4, l = tid & 15;
        const float4* ap = (const float4*)(agg + (size_t)(nodeBase + g) * HID + l * 8);
        float4 a0 = ap[0], a1 = ap[1];
        aT[l*8+0][g] = a0.x; aT[l*8+1][g] = a0.y; aT[l*8+2][g] = a0.z; aT[l*8+3][g] = a0.w;
        aT[l*8+4][g] = a1.x; aT[l*8+5][g] = a1.y; aT[l*8+6][g] = a1.z; aT[l*8+7][g] = a1.w;
    }
    __syncthreads();

    const int c = tid & 127, half = tid >> 7;
    {
        float4 acc0 = {0,0,0,0}, acc1 = {0,0,0,0};
        for (int i = 0; i < HID; i++) {
            float w = Wo[i * HID + c];
            const float4* ar = (const float4*)&aT[i][half * 8];
            acc0 = f4fma(w, ar[0], acc0);
            acc1 = f4fma(w, ar[1], acc1);
        }
        float av[8] = {acc0.x, acc0.y, acc0.z, acc0.w, acc1.x, acc1.y, acc1.z, acc1.w};
        float bc = bo[c];
#pragma unroll
        for (int n = 0; n < 8; n++) {
            int node = nodeBase + half * 8 + n;
            size_t idx = (size_t)node * HID + c;
            float o = av[n] + bc;
            x1T[c][half * 8 + n] = x[idx] + gamma[idx] * o + beta[idx];
        }
    }
    __syncthreads();

    {
        int g = tid >> 4, l = tid & 15;
        float s = 0.f, ss = 0.f;
#pragma unroll
        for (int k = 0; k < 8; k++) {
            float v = x1T[l + 16 * k][g];
            s += v; ss += v * v;
        }
#pragma unroll
        for (int m = 1; m < 16; m <<= 1) { s += __shfl_xor(s, m); ss += __shfl_xor(ss, m); }
        if (l == 0) {
            float mean = s * (1.f / HID);
            mu[g] = mean;
            ri[g] = rsqrtf(ss * (1.f / HID) - mean * mean + 1e-5f);
        }
    }
    __syncthreads();

    {
        int g = tid >> 4, l = tid & 15;
        float mean = mu[g], r = ri[g];
#pragma unroll
        for (int k = 0; k < 8; k++) {
            int i = l * 8 + k;
            aT[i][g] = (x1T[i][g] - mean) * r * g2[i] + b2[i];
        }
    }
    __syncthreads();

    {
        float4 acc0 = {0,0,0,0}, acc1 = {0,0,0,0}, acc2 = {0,0,0,0}, acc3 = {0,0,0,0};
        for (int i = 0; i < HID; i++) {
            float w = fw1[i * 256 + tid];
            const float4* ar = (const float4*)&aT[i][0];
            acc0 = f4fma(w, ar[0], acc0);
            acc1 = f4fma(w, ar[1], acc1);
            acc2 = f4fma(w, ar[2], acc2);
            acc3 = f4fma(w, ar[3], acc3);
        }
        float fb = fb1[tid];
        float av[16] = {acc0.x, acc0.y, acc0.z, acc0.w, acc1.x, acc1.y, acc1.z, acc1.w,
                        acc2.x, acc2.y, acc2.z, acc2.w, acc3.x, acc3.y, acc3.z, acc3.w};
#pragma unroll
        for (int n = 0; n < 16; n++) f1T[tid][n] = gelu_f(av[n] + fb);
    }
    __syncthreads();

    {
        float4 acc0 = {0,0,0,0}, acc1 = {0,0,0,0};
        for (int i = 0; i < 2 * HID; i++) {
            float w = fw2[i * HID + c];
            const float4* fr = (const float4*)&f1T[i][half * 8];
            acc0 = f4fma(w, fr[0], acc0);
            acc1 = f4fma(w, fr[1], acc1);
        }
        float av[8] = {acc0.x, acc0.y, acc0.z, acc0.w, acc1.x, acc1.y, acc1.z, acc1.w};
        float fb = fb2[c];
#pragma unroll
        for (int n = 0; n < 8; n++) {
            int node = nodeBase + half * 8 + n;
            out[(size_t)node * HID + c] = x1T[c][half * 8 + n] + av[n] + fb;
        }
    }
}

// ---------------------------------------------------------------------------
extern "C" void kernel_launch(void* const* d_in, const int* in_sizes, int n_in,
                              void* d_out, int out_size, void* d_ws, size_t ws_size,
                              hipStream_t stream)
{
    const float* x         = (const float*)d_in[0];
    const float* edge_attr = (const float*)d_in[1];
    const float* gamma     = (const float*)d_in[2];
    const float* beta      = (const float*)d_in[3];
    const float* Wq        = (const float*)d_in[4];
    const float* Wk        = (const float*)d_in[5];
    const float* Wv        = (const float*)d_in[6];
    const float* Wo        = (const float*)d_in[7];
    const float* bo        = (const float*)d_in[8];
    const float* ea_w1     = (const float*)d_in[9];
    const float* ea_b1     = (const float*)d_in[10];
    const float* ea_w2     = (const float*)d_in[11];
    const float* ea_b2     = (const float*)d_in[12];
    const float* eg_w1     = (const float*)d_in[13];
    const float* eg_b1     = (const float*)d_in[14];
    const float* eg_w2     = (const float*)d_in[15];
    const float* eg_b2     = (const float*)d_in[16];
    const float* ln1_g     = (const float*)d_in[17];
    const float* ln1_b     = (const float*)d_in[18];
    const float* ln2_g     = (const float*)d_in[19];
    const float* ln2_b     = (const float*)d_in[20];
    const float* fw1       = (const float*)d_in[21];
    const float* fb1       = (const float*)d_in[22];
    const float* fw2       = (const float*)d_in[23];
    const float* fb2       = (const float*)d_in[24];
    const int*   ei        = (const int*)d_in[25];

    char* wsb = (char*)d_ws;
    size_t off = 0;
    auto alloc = [&](size_t bytes) { void* p = wsb + off; off += (bytes + 255) & ~(size_t)255; return p; };

    float* Qb     = (float*)alloc((size_t)N * HID * 4);
    float* Kb     = (float*)alloc((size_t)N * HID * 4);
    float* Vb     = (float*)alloc((size_t)N * HID * 4);
    float* logit  = (float*)alloc((size_t)E * NH * 4);
    float* marr   = (float*)alloc((size_t)N * NH * 4);
    float* rsarr  = (float*)alloc((size_t)N * NH * 4);
    float* aggb   = (float*)alloc((size_t)N * HID * 4);
    int*   cnt    = (int*)alloc((size_t)N * 4);
    int*   starts = (int*)alloc((size_t)(N + 1) * 4);
    int*   cursor = (int*)alloc((size_t)N * 4);
    int*   bsum   = (int*)alloc((size_t)NB * 4);
    int*   boff   = (int*)alloc((size_t)NB * 4);
    int*   perm   = (int*)alloc((size_t)E * 4);
    unsigned int* wvb = (unsigned int*)alloc((size_t)E * 64 * 4);
    unsigned short* w1ea = (unsigned short*)alloc(2048 * 2);
    unsigned short* w2ea = (unsigned short*)alloc(1024 * 2);
    unsigned short* w1eg = (unsigned short*)alloc(2048 * 2);
    unsigned short* w2eg = (unsigned short*)alloc(8192 * 2);
    float* outp   = (float*)d_out;

    hipMemsetAsync(cnt, 0, (size_t)N * sizeof(int), stream);

    const int EB = (E + 255) / 256;
    k_cvt_w<<<32, 256, 0, stream>>>(ea_w1, ea_w2, eg_w1, eg_w2, w1ea, w2ea, w1eg, w2eg);
    k_ln_qkv<<<N / 16, 256, 0, stream>>>(x, ln1_g, ln1_b, Wq, Wk, Wv, Qb, Kb, Vb);
    k_hist<<<EB, 256, 0, stream>>>(ei, cnt);
    k_bsum<<<NB, 256, 0, stream>>>(cnt, bsum);
    k_scan_b<<<1, 256, 0, stream>>>(bsum, boff);
    k_scan_final<<<NB, 256, 0, stream>>>(cnt, boff, starts, cursor);
    k_scatter<<<EB, 256, 0, stream>>>(ei, cursor, perm);
    k_logits_mfma<<<EB, 256, 0, stream>>>(edge_attr, ei, Qb, Kb,
                                          w1ea, ea_b1, w2ea, ea_b2, logit);
    k_softmax<<<(N * NH + 255) / 256, 256, 0, stream>>>(starts, perm, logit, marr, rsarr);
    k_weighted_mfma<<<EB, 256, 0, stream>>>(edge_attr, ei, Vb,
                                            w1eg, eg_b1, w2eg, eg_b2,
                                            logit, marr, rsarr, wvb);
    k_agg<<<(N + 3) / 4, 256, 0, stream>>>(starts, perm, wvb, aggb);
    k_node_out<<<N / 16, 256, 0, stream>>>(x, gamma, beta, Wo, bo, ln2_g, ln2_b,
                                           fw1, fb1, fw2, fb2, aggb, outp);
}

// Round 4
// 736.039 us; speedup vs baseline: 6.1568x; 1.1706x over previous
//
#include <hip/hip_runtime.h>

constexpr int N   = 50000;
constexpr int E   = 500000;
constexpr int HID = 128;
constexpr int NH  = 8;
constexpr int ED  = 32;
constexpr int EGD = 64;
constexpr int NB  = (N + 255) / 256;

typedef short  bf16x8 __attribute__((ext_vector_type(8)));
typedef float  f32x4  __attribute__((ext_vector_type(4)));

__device__ __forceinline__ float gelu_f(float v) {
    return 0.5f * v * (1.f + erff(v * 0.70710678118654752f));
}
__device__ __forceinline__ float sigm_f(float v) {
    return 1.f / (1.f + __expf(-v));
}
__device__ __forceinline__ unsigned short f2bf(float f) {
    unsigned int u = __float_as_uint(f);
    return (unsigned short)((u + 0x7fffu + ((u >> 16) & 1u)) >> 16);
}

// ---------------------------------------------------------------------------
// Weight conversion: all weight matrices -> bf16 MFMA B-fragment order.
// Fragment f=(nt*KT+ks)*64+lane holds 8 contiguous bf16:
//   elem j = W[ks*32+(lane>>4)*8+j][nt*16+(lane&15)]  (0 if col >= srcN)
// Layout in dst (frag index bases):
//   Wq 0 | Wk 2048 | Wv 4096 | Wo 6144 | fw1 8192 | fw2 12288
//   w1ea 16384 | w2ea 16640 | w1eg 16768 | w2eg 17024 | end 18048
// ---------------------------------------------------------------------------
__global__ __launch_bounds__(256) void k_cvt(
    const float* __restrict__ Wq, const float* __restrict__ Wk,
    const float* __restrict__ Wv, const float* __restrict__ Wo,
    const float* __restrict__ fw1, const float* __restrict__ fw2,
    const float* __restrict__ ea_w1, const float* __restrict__ ea_w2,
    const float* __restrict__ eg_w1, const float* __restrict__ eg_w2,
    unsigned short* __restrict__ dst)
{
    int f = blockIdx.x * 256 + threadIdx.x;
    if (f >= 18048) return;
    const float* W; int KT, srcN, base;
    if      (f < 2048)  { W = Wq;    KT = 4; srcN = 128; base = 0; }
    else if (f < 4096)  { W = Wk;    KT = 4; srcN = 128; base = 2048; }
    else if (f < 6144)  { W = Wv;    KT = 4; srcN = 128; base = 4096; }
    else if (f < 8192)  { W = Wo;    KT = 4; srcN = 128; base = 6144; }
    else if (f < 12288) { W = fw1;   KT = 4; srcN = 256; base = 8192; }
    else if (f < 16384) { W = fw2;   KT = 8; srcN = 128; base = 12288; }
    else if (f < 16640) { W = ea_w1; KT = 1; srcN = 64;  base = 16384; }
    else if (f < 16768) { W = ea_w2; KT = 2; srcN = 8;   base = 16640; }
    else if (f < 17024) { W = eg_w1; KT = 1; srcN = 64;  base = 16768; }
    else                { W = eg_w2; KT = 2; srcN = 128; base = 17024; }
    int fl = f - base, lane = fl & 63, t = fl >> 6;
    int ks = t % KT, nt = t / KT;
    int n  = nt * 16 + (lane & 15);
    int k0 = ks * 32 + (lane >> 4) * 8;
    union { unsigned short u[8]; uint4 v; } o;
#pragma unroll
    for (int j = 0; j < 8; j++)
        o.u[j] = (n < srcN) ? f2bf(W[(size_t)(k0 + j) * srcN + n]) : (unsigned short)0;
    *(uint4*)(dst + (size_t)f * 8) = o.v;
}

// ---------------------------------------------------------------------------
// LN1 + QKV via MFMA. 64 nodes per 256-thread block, 16 nodes per wave.
// ---------------------------------------------------------------------------
__global__ __launch_bounds__(256) void k_ln_qkv_mfma(
    const float* __restrict__ x, const float* __restrict__ g1, const float* __restrict__ b1,
    const unsigned short* __restrict__ wqkv,   // frag-order Wq|Wk|Wv
    float* __restrict__ Q, float* __restrict__ K, float* __restrict__ V)
{
    __shared__ unsigned short xn_lds[64 * 128];   // swizzled granules of 8
    const int tid = threadIdx.x;
    const int nodeBase = blockIdx.x * 64;

    // LN1: 4 threads per node, 32 elems each
    {
        int nl = tid >> 2, q = tid & 3;
        int gn = nodeBase + nl; if (gn >= N) gn = N - 1;
        const float4* xp = (const float4*)(x + (size_t)gn * HID + q * 32);
        float xv[32]; float s = 0.f, ss = 0.f;
#pragma unroll
        for (int i = 0; i < 8; i++) {
            float4 t = xp[i];
            xv[4*i] = t.x; xv[4*i+1] = t.y; xv[4*i+2] = t.z; xv[4*i+3] = t.w;
        }
#pragma unroll
        for (int i = 0; i < 32; i++) { s += xv[i]; ss += xv[i] * xv[i]; }
        s += __shfl_xor(s, 1); ss += __shfl_xor(ss, 1);
        s += __shfl_xor(s, 2); ss += __shfl_xor(ss, 2);
        float mean = s * (1.f / HID);
        float ri = rsqrtf(ss * (1.f / HID) - mean * mean + 1e-5f);
#pragma unroll
        for (int j = 0; j < 4; j++) {
            union { unsigned short u[8]; uint4 v4; } o;
#pragma unroll
            for (int c = 0; c < 8; c++) {
                int col = q * 32 + j * 8 + c;
                o.u[c] = f2bf((xv[j*8+c] - mean) * ri * g1[col] + b1[col]);
            }
            int phys = (q * 4 + j) ^ (nl & 15);
            *(uint4*)&xn_lds[nl * 128 + phys * 8] = o.v4;
        }
    }
    __syncthreads();

    const int lane = tid & 63, w = tid >> 6, lm = lane & 15, kb = lane >> 4;
    bf16x8 af[4];
#pragma unroll
    for (int ks = 0; ks < 4; ks++)
        af[ks] = *(const bf16x8*)&xn_lds[(w * 16 + lm) * 128 + ((ks * 4 + kb) ^ lm) * 8];

    for (int nt = 0; nt < 24; nt++) {
        f32x4 c = {0.f, 0.f, 0.f, 0.f};
#pragma unroll
        for (int ks = 0; ks < 4; ks++)
            c = __builtin_amdgcn_mfma_f32_16x16x32_bf16(
                    af[ks], *(const bf16x8*)&wqkv[((size_t)(nt * 4 + ks) * 64 + lane) * 8],
                    c, 0, 0, 0);
        float* O = (nt < 8) ? Q : ((nt < 16) ? K : V);
        int cc = (nt & 7) * 16 + lm;
#pragma unroll
        for (int r = 0; r < 4; r++) {
            int node = nodeBase + w * 16 + kb * 4 + r;
            if (node < N) O[(size_t)node * HID + cc] = c[r];
        }
    }
}

// ---------------------------------------------------------------------------
// Sorting: histogram -> scan -> scatter perm
// ---------------------------------------------------------------------------
__global__ __launch_bounds__(256) void k_hist(const int* __restrict__ ei, int* __restrict__ cnt) {
    int e = blockIdx.x * 256 + threadIdx.x;
    if (e < E) atomicAdd(&cnt[ei[E + e]], 1);
}

__global__ __launch_bounds__(256) void k_bsum(const int* __restrict__ cnt, int* __restrict__ bsum) {
    int i = blockIdx.x * 256 + threadIdx.x;
    int v = (i < N) ? cnt[i] : 0;
#pragma unroll
    for (int m = 1; m < 64; m <<= 1) v += __shfl_xor(v, m);
    __shared__ int ws4[4];
    if ((threadIdx.x & 63) == 0) ws4[threadIdx.x >> 6] = v;
    __syncthreads();
    if (threadIdx.x == 0) bsum[blockIdx.x] = ws4[0] + ws4[1] + ws4[2] + ws4[3];
}

__global__ __launch_bounds__(256) void k_scan_b(const int* __restrict__ bsum, int* __restrict__ boff) {
    __shared__ int s[256];
    int t = threadIdx.x;
    int v = (t < NB) ? bsum[t] : 0;
    s[t] = v; __syncthreads();
    for (int off = 1; off < 256; off <<= 1) {
        int add = (t >= off) ? s[t - off] : 0;
        __syncthreads();
        s[t] += add;
        __syncthreads();
    }
    if (t < NB) boff[t] = s[t] - v;
}

__global__ __launch_bounds__(256) void k_scan_final(
    const int* __restrict__ cnt, const int* __restrict__ boff,
    int* __restrict__ starts, int* __restrict__ cursor)
{
    __shared__ int s[256];
    int t = threadIdx.x, i = blockIdx.x * 256 + t;
    int v = (i < N) ? cnt[i] : 0;
    s[t] = v; __syncthreads();
    for (int off = 1; off < 256; off <<= 1) {
        int add = (t >= off) ? s[t - off] : 0;
        __syncthreads();
        s[t] += add;
        __syncthreads();
    }
    int ex = boff[blockIdx.x] + s[t] - v;
    if (i < N) {
        starts[i] = ex;
        cursor[i] = ex;
        if (i == N - 1) starts[N] = ex + v;
    }
}

__global__ __launch_bounds__(256) void k_scatter(
    const int* __restrict__ ei, int* __restrict__ cursor, int* __restrict__ perm)
{
    int e = blockIdx.x * 256 + threadIdx.x;
    if (e < E) {
        int p = atomicAdd(&cursor[ei[E + e]], 1);
        perm[p] = e;
    }
}

// ---------------------------------------------------------------------------
// MFMA edge-MLP logits: gelu(ea@w1+b1)@w2 + b2 + 0.25*QK -> logit[E][8]
// ---------------------------------------------------------------------------
__global__ __launch_bounds__(256) void k_logits_mfma(
    const float* __restrict__ edge_attr, const int* __restrict__ ei,
    const float* __restrict__ Q, const float* __restrict__ K,
    const unsigned short* __restrict__ w1b, const float* __restrict__ b1,
    const unsigned short* __restrict__ w2b, const float* __restrict__ b2,
    float* __restrict__ logit)
{
    __shared__ unsigned short ea_lds[256 * 32];
    __shared__ unsigned short hid_lds[256 * 64];
    __shared__ float st8[256 * 8];

    const int tid = threadIdx.x;
    const int eBase = blockIdx.x * 256;
    const int lane = tid & 63;
    const int wv = tid >> 6;
    const int wBase = wv * 64;
    const int lm = lane & 15;
    const int kb = lane >> 4;
    const int rowq = kb * 4;

#pragma unroll
    for (int it = 0; it < 8; it++) {
        int idx = it * 256 + tid;
        int e = idx >> 3, c = (idx & 7) * 4;
        int ge = eBase + e; if (ge >= E) ge = E - 1;
        float4 v = *(const float4*)(edge_attr + (size_t)ge * ED + c);
        int g = ((c >> 3) ^ (e & 3));
        unsigned short* p = &ea_lds[e * 32 + g * 8 + (c & 7)];
        p[0] = f2bf(v.x); p[1] = f2bf(v.y); p[2] = f2bf(v.z); p[3] = f2bf(v.w);
    }
    __syncthreads();

    bf16x8 a1[4];
#pragma unroll
    for (int mt = 0; mt < 4; mt++) {
        int m = wBase + mt * 16 + lm;
        a1[mt] = *(const bf16x8*)&ea_lds[m * 32 + (kb ^ (m & 3)) * 8];
    }
    f32x4 acc1[4][4];
#pragma unroll
    for (int mt = 0; mt < 4; mt++)
#pragma unroll
        for (int nt = 0; nt < 4; nt++) {
            f32x4 z = {0.f, 0.f, 0.f, 0.f};
            acc1[mt][nt] = __builtin_amdgcn_mfma_f32_16x16x32_bf16(
                a1[mt], *(const bf16x8*)&w1b[(nt * 64 + lane) * 8], z, 0, 0, 0);
        }
#pragma unroll
    for (int nt = 0; nt < 4; nt++) {
        float bias = b1[nt * 16 + lm];
#pragma unroll
        for (int mt = 0; mt < 4; mt++)
#pragma unroll
            for (int r = 0; r < 4; r++) {
                int row = wBase + mt * 16 + rowq + r;
                int col = nt * 16 + lm;
                int g = (col >> 3) ^ (row & 7);
                hid_lds[row * 64 + g * 8 + (col & 7)] = f2bf(gelu_f(acc1[mt][nt][r] + bias));
            }
    }

    bf16x8 a2[4][2];
#pragma unroll
    for (int mt = 0; mt < 4; mt++)
#pragma unroll
        for (int ks = 0; ks < 2; ks++) {
            int m = wBase + mt * 16 + lm;
            int g = (ks * 4 + kb) ^ (m & 7);
            a2[mt][ks] = *(const bf16x8*)&hid_lds[m * 64 + g * 8];
        }
    {
        float bias = b2[lm & 7];
#pragma unroll
        for (int mt = 0; mt < 4; mt++) {
            f32x4 acc = {bias, bias, bias, bias};
            acc = __builtin_amdgcn_mfma_f32_16x16x32_bf16(
                a2[mt][0], *(const bf16x8*)&w2b[(0 * 64 + lane) * 8], acc, 0, 0, 0);
            acc = __builtin_amdgcn_mfma_f32_16x16x32_bf16(
                a2[mt][1], *(const bf16x8*)&w2b[(1 * 64 + lane) * 8], acc, 0, 0, 0);
            if (lm < 8) {
#pragma unroll
                for (int r = 0; r < 4; r++)
                    st8[(wBase + mt * 16 + rowq + r) * 8 + lm] = acc[r];
            }
        }
    }
    __syncthreads();

    int e = eBase + tid;
    if (e < E) {
        int src = ei[e], dst = ei[E + e];
        const float4* qp = (const float4*)(Q + (size_t)dst * HID);
        const float4* kp = (const float4*)(K + (size_t)src * HID);
        float lg[8];
#pragma unroll
        for (int h = 0; h < 8; h++) {
            float dot = 0.f;
#pragma unroll
            for (int t = 0; t < 4; t++) {
                float4 q = qp[h * 4 + t], k4 = kp[h * 4 + t];
                dot += q.x * k4.x + q.y * k4.y + q.z * k4.z + q.w * k4.w;
            }
            lg[h] = st8[tid * 8 + h] + 0.25f * dot;
        }
        float4* op = (float4*)(logit + (size_t)e * NH);
        op[0] = make_float4(lg[0], lg[1], lg[2], lg[3]);
        op[1] = make_float4(lg[4], lg[5], lg[6], lg[7]);
    }
}

// ---------------------------------------------------------------------------
// Segment softmax stats: one thread per (dst, h).
// ---------------------------------------------------------------------------
__global__ __launch_bounds__(256) void k_softmax(
    const int* __restrict__ starts, const int* __restrict__ perm,
    const float* __restrict__ logit, float* __restrict__ marr, float* __restrict__ rsarr)
{
    int i = blockIdx.x * 256 + threadIdx.x;
    if (i >= N * NH) return;
    int dst = i >> 3, h = i & 7;
    int s0 = starts[dst], s1 = starts[dst + 1];
    float m = 0.f;
    for (int j = s0; j < s1; j++)
        m = fmaxf(m, logit[(size_t)perm[j] * NH + h]);
    float s = 0.f;
    for (int j = s0; j < s1; j++)
        s += __expf(logit[(size_t)perm[j] * NH + h] - m);
    marr[i] = m;
    rsarr[i] = 1.f / (s + 1e-10f);
}

// ---------------------------------------------------------------------------
// MFMA gate MLP + attn*sigmoid(gate)*V[src] -> weighted[E][128] bf16.
// ---------------------------------------------------------------------------
__global__ __launch_bounds__(256) void k_weighted_mfma(
    const float* __restrict__ edge_attr, const int* __restrict__ ei,
    const float* __restrict__ Vb,
    const unsigned short* __restrict__ w1b, const float* __restrict__ b1,
    const unsigned short* __restrict__ w2b, const float* __restrict__ b2,
    const float* __restrict__ logit, const float* __restrict__ marr,
    const float* __restrict__ rsarr, unsigned int* __restrict__ wout)
{
    __shared__ unsigned short ea_lds[256 * 32];
    __shared__ unsigned short hid_lds[256 * 64];
    __shared__ float attn_lds[256 * 8];
    __shared__ int src_lds[256];

    const int tid = threadIdx.x;
    const int eBase = blockIdx.x * 256;
    const int lane = tid & 63;
    const int wv = tid >> 6;
    const int wBase = wv * 64;
    const int lm = lane & 15;
    const int kb = lane >> 4;
    const int rowq = kb * 4;

#pragma unroll
    for (int it = 0; it < 8; it++) {
        int idx = it * 256 + tid;
        int e = idx >> 3, c = (idx & 7) * 4;
        int ge = eBase + e; if (ge >= E) ge = E - 1;
        float4 v = *(const float4*)(edge_attr + (size_t)ge * ED + c);
        int g = ((c >> 3) ^ (e & 3));
        unsigned short* p = &ea_lds[e * 32 + g * 8 + (c & 7)];
        p[0] = f2bf(v.x); p[1] = f2bf(v.y); p[2] = f2bf(v.z); p[3] = f2bf(v.w);
    }
    {
        int e = eBase + tid; if (e >= E) e = E - 1;
        int src = ei[e], dst = ei[E + e];
        src_lds[tid] = src;
        const float4* lp = (const float4*)(logit + (size_t)e * NH);
        const float4* mp = (const float4*)(marr + (size_t)dst * NH);
        const float4* rp = (const float4*)(rsarr + (size_t)dst * NH);
#pragma unroll
        for (int q = 0; q < 2; q++) {
            float4 l4 = lp[q], m4 = mp[q], r4 = rp[q];
            float4 a4;
            a4.x = __expf(l4.x - m4.x) * r4.x;
            a4.y = __expf(l4.y - m4.y) * r4.y;
            a4.z = __expf(l4.z - m4.z) * r4.z;
            a4.w = __expf(l4.w - m4.w) * r4.w;
            *(float4*)&attn_lds[tid * 8 + q * 4] = a4;
        }
    }
    __syncthreads();

    bf16x8 a1[4];
#pragma unroll
    for (int mt = 0; mt < 4; mt++) {
        int m = wBase + mt * 16 + lm;
        a1[mt] = *(const bf16x8*)&ea_lds[m * 32 + (kb ^ (m & 3)) * 8];
    }
    f32x4 acc1[4][4];
#pragma unroll
    for (int mt = 0; mt < 4; mt++)
#pragma unroll
        for (int nt = 0; nt < 4; nt++) {
            f32x4 z = {0.f, 0.f, 0.f, 0.f};
            acc1[mt][nt] = __builtin_amdgcn_mfma_f32_16x16x32_bf16(
                a1[mt], *(const bf16x8*)&w1b[(nt * 64 + lane) * 8], z, 0, 0, 0);
        }
#pragma unroll
    for (int nt = 0; nt < 4; nt++) {
        float bias = b1[nt * 16 + lm];
#pragma unroll
        for (int mt = 0; mt < 4; mt++)
#pragma unroll
            for (int r = 0; r < 4; r++) {
                int row = wBase + mt * 16 + rowq + r;
                int col = nt * 16 + lm;
                int g = (col >> 3) ^ (row & 7);
                hid_lds[row * 64 + g * 8 + (col & 7)] = f2bf(gelu_f(acc1[mt][nt][r] + bias));
            }
    }

    bf16x8 a2[4][2];
#pragma unroll
    for (int mt = 0; mt < 4; mt++)
#pragma unroll
        for (int ks = 0; ks < 2; ks++) {
            int m = wBase + mt * 16 + lm;
            int g = (ks * 4 + kb) ^ (m & 7);
            a2[mt][ks] = *(const bf16x8*)&hid_lds[m * 64 + g * 8];
        }

#pragma unroll 1
    for (int ch = 0; ch < 4; ch++) {
        const int cc = ch * 32;
        f32x4 acc[4][2];
#pragma unroll
        for (int nt = 0; nt < 2; nt++) {
            float bias = b2[cc + nt * 16 + lm];
            const bf16x8 bf0 = *(const bf16x8*)&w2b[(((ch * 2 + nt) * 2 + 0) * 64 + lane) * 8];
            const bf16x8 bf1 = *(const bf16x8*)&w2b[(((ch * 2 + nt) * 2 + 1) * 64 + lane) * 8];
#pragma unroll
            for (int mt = 0; mt < 4; mt++) {
                f32x4 c = {bias, bias, bias, bias};
                c = __builtin_amdgcn_mfma_f32_16x16x32_bf16(a2[mt][0], bf0, c, 0, 0, 0);
                c = __builtin_amdgcn_mfma_f32_16x16x32_bf16(a2[mt][1], bf1, c, 0, 0, 0);
                acc[mt][nt] = c;
            }
        }
        __syncthreads();
#pragma unroll
        for (int nt = 0; nt < 2; nt++) {
            int head = ch * 2 + nt;
#pragma unroll
            for (int mt = 0; mt < 4; mt++)
#pragma unroll
                for (int r = 0; r < 4; r++) {
                    int em = wBase + mt * 16 + rowq + r;
                    float a = attn_lds[em * 8 + head];
                    int src = src_lds[em];
                    float vval = Vb[(size_t)src * HID + cc + nt * 16 + lm];
                    float w = a * sigm_f(acc[mt][nt][r]) * vval;
                    int cl = nt * 16 + lm;
                    int g = (cl >> 3) ^ (em & 3);
                    ea_lds[em * 32 + g * 8 + (cl & 7)] = f2bf(w);
                }
        }
        __syncthreads();
#pragma unroll
        for (int it = 0; it < 4; it++) {
            int idx = it * 256 + tid;
            int el = idx >> 2, q = idx & 3;
            if (eBase + el < E) {
                int g = q ^ (el & 3);
                uint4 u = *(const uint4*)&ea_lds[el * 32 + g * 8];
                *(uint4*)(wout + (size_t)(eBase + el) * 64 + ch * 16 + q * 4) = u;
            }
        }
    }
}

// ---------------------------------------------------------------------------
// Kernel D: segment-sum of weighted rows. One wave per dst.
// ---------------------------------------------------------------------------
__global__ __launch_bounds__(256) void k_agg(
    const int* __restrict__ starts, const int* __restrict__ perm,
    const unsigned int* __restrict__ wv, float* __restrict__ agg)
{
    int wave = threadIdx.x >> 6, lane = threadIdx.x & 63;
    int dst = blockIdx.x * 4 + wave;
    if (dst >= N) return;
    int s0 = starts[dst], s1 = starts[dst + 1];
    float ax = 0.f, ay = 0.f;
    for (int j = s0; j < s1; j++) {
        int e = perm[j];
        unsigned int u = wv[(size_t)e * 64 + lane];
        ax += __uint_as_float(u << 16);
        ay += __uint_as_float(u & 0xffff0000u);
    }
    float2* o = (float2*)(agg + (size_t)dst * HID + lane * 2);
    *o = make_float2(ax, ay);
}

// ---------------------------------------------------------------------------
// Node epilogue via MFMA: agg@Wo + gamma/beta + residual + LN2 + FFN + residual.
// 64 nodes per 256-thread block; waves own 16-row tiles end to end.
// x1 stays in registers (C-layout); LN2 stats via shfl over the lm group.
// ---------------------------------------------------------------------------
__global__ __launch_bounds__(256) void k_node_out_mfma(
    const float* __restrict__ x, const float* __restrict__ gamma, const float* __restrict__ beta,
    const unsigned short* __restrict__ wo_f, const float* __restrict__ bo,
    const float* __restrict__ g2, const float* __restrict__ b2,
    const unsigned short* __restrict__ fw1_f, const float* __restrict__ fb1,
    const unsigned short* __restrict__ fw2_f, const float* __restrict__ fb2,
    const float* __restrict__ agg, float* __restrict__ out)
{
    __shared__ unsigned short a_lds[64 * 128];    // agg bf16, then x2 bf16
    __shared__ unsigned short f1_lds[64 * 256];   // gelu(ffn1) bf16
    const int tid = threadIdx.x;
    const int nodeBase = blockIdx.x * 64;

    // stage agg -> bf16 swizzled
    {
        int nl = tid >> 2, q = tid & 3;
        int gn = nodeBase + nl; if (gn >= N) gn = N - 1;
        const float4* ap = (const float4*)(agg + (size_t)gn * HID + q * 32);
#pragma unroll
        for (int j = 0; j < 4; j++) {
            float4 t0 = ap[2 * j], t1 = ap[2 * j + 1];
            union { unsigned short u[8]; uint4 v4; } o;
            o.u[0] = f2bf(t0.x); o.u[1] = f2bf(t0.y); o.u[2] = f2bf(t0.z); o.u[3] = f2bf(t0.w);
            o.u[4] = f2bf(t1.x); o.u[5] = f2bf(t1.y); o.u[6] = f2bf(t1.z); o.u[7] = f2bf(t1.w);
            int phys = (q * 4 + j) ^ (nl & 15);
            *(uint4*)&a_lds[nl * 128 + phys * 8] = o.v4;
        }
    }
    __syncthreads();

    const int lane = tid & 63, w = tid >> 6, lm = lane & 15, kb = lane >> 4;
    const int rowLoc = w * 16;

    // GEMM1: agg @ Wo
    f32x4 xo[8];
    {
        bf16x8 af[4];
#pragma unroll
        for (int ks = 0; ks < 4; ks++)
            af[ks] = *(const bf16x8*)&a_lds[(rowLoc + lm) * 128 + ((ks * 4 + kb) ^ lm) * 8];
#pragma unroll
        for (int nt = 0; nt < 8; nt++) {
            f32x4 c = {0.f, 0.f, 0.f, 0.f};
#pragma unroll
            for (int ks = 0; ks < 4; ks++)
                c = __builtin_amdgcn_mfma_f32_16x16x32_bf16(
                        af[ks], *(const bf16x8*)&wo_f[((size_t)(nt * 4 + ks) * 64 + lane) * 8],
                        c, 0, 0, 0);
            xo[nt] = c;
        }
    }

    // epilogue1: x1 = x + gamma*(o+bo) + beta  (registers, C-layout)
    float x1v[8][4];
#pragma unroll
    for (int nt = 0; nt < 8; nt++) {
        int col = nt * 16 + lm;
        float boc = bo[col];
#pragma unroll
        for (int r = 0; r < 4; r++) {
            int node = nodeBase + rowLoc + kb * 4 + r; if (node >= N) node = N - 1;
            size_t idx = (size_t)node * HID + col;
            x1v[nt][r] = x[idx] + gamma[idx] * (xo[nt][r] + boc) + beta[idx];
        }
    }

    // LN2 stats per row via shfl over lm group
    float s4[4] = {0,0,0,0}, q4[4] = {0,0,0,0};
#pragma unroll
    for (int nt = 0; nt < 8; nt++)
#pragma unroll
        for (int r = 0; r < 4; r++) { s4[r] += x1v[nt][r]; q4[r] += x1v[nt][r] * x1v[nt][r]; }
#pragma unroll
    for (int m = 1; m < 16; m <<= 1)
#pragma unroll
        for (int r = 0; r < 4; r++) { s4[r] += __shfl_xor(s4[r], m); q4[r] += __shfl_xor(q4[r], m); }
    float mu4[4], ri4[4];
#pragma unroll
    for (int r = 0; r < 4; r++) {
        float mu = s4[r] * (1.f / HID);
        mu4[r] = mu;
        ri4[r] = rsqrtf(q4[r] * (1.f / HID) - mu * mu + 1e-5f);
    }

    // x2 bf16 -> a_lds (own rows)
#pragma unroll
    for (int nt = 0; nt < 8; nt++) {
        int col = nt * 16 + lm;
        float g2c = g2[col], b2c = b2[col];
#pragma unroll
        for (int r = 0; r < 4; r++) {
            float xn = (x1v[nt][r] - mu4[r]) * ri4[r] * g2c + b2c;
            int row = rowLoc + kb * 4 + r;
            int g = col >> 3;
            a_lds[row * 128 + (g ^ (row & 15)) * 8 + (col & 7)] = f2bf(xn);
        }
    }
    __syncthreads();

    // GEMM2: x2 @ fw1, gelu -> f1_lds
    {
        bf16x8 af[4];
#pragma unroll
        for (int ks = 0; ks < 4; ks++)
            af[ks] = *(const bf16x8*)&a_lds[(rowLoc + lm) * 128 + ((ks * 4 + kb) ^ lm) * 8];
#pragma unroll
        for (int nt = 0; nt < 16; nt++) {
            f32x4 c = {0.f, 0.f, 0.f, 0.f};
#pragma unroll
            for (int ks = 0; ks < 4; ks++)
                c = __builtin_amdgcn_mfma_f32_16x16x32_bf16(
                        af[ks], *(const bf16x8*)&fw1_f[((size_t)(nt * 4 + ks) * 64 + lane) * 8],
                        c, 0, 0, 0);
            int col = nt * 16 + lm;
            float fbc = fb1[col];
#pragma unroll
            for (int r = 0; r < 4; r++) {
                int row = rowLoc + kb * 4 + r;
                int g = col >> 3;
                int phys = (g & 16) | ((g ^ (row & 15)) & 15);
                f1_lds[row * 256 + phys * 8 + (col & 7)] = f2bf(gelu_f(c[r] + fbc));
            }
        }
    }
    __syncthreads();

    // GEMM3: f1 @ fw2, + fb2 + x1 -> out
    {
        bf16x8 af[8];
#pragma unroll
        for (int ks = 0; ks < 8; ks++) {
            int g = ks * 4 + kb;
            int phys = (g & 16) | ((g ^ lm) & 15);
            af[ks] = *(const bf16x8*)&f1_lds[(rowLoc + lm) * 256 + phys * 8];
        }
#pragma unroll
        for (int nt = 0; nt < 8; nt++) {
            f32x4 c = {0.f, 0.f, 0.f, 0.f};
#pragma unroll
            for (int ks = 0; ks < 8; ks++)
                c = __builtin_amdgcn_mfma_f32_16x16x32_bf16(
                        af[ks], *(const bf16x8*)&fw2_f[((size_t)(nt * 8 + ks) * 64 + lane) * 8],
                        c, 0, 0, 0);
            int col = nt * 16 + lm;
            float fbc = fb2[col];
#pragma unroll
            for (int r = 0; r < 4; r++) {
                int node = nodeBase + rowLoc + kb * 4 + r;
                if (node < N) out[(size_t)node * HID + col] = x1v[nt][r] + c[r] + fbc;
            }
        }
    }
}

// ---------------------------------------------------------------------------
extern "C" void kernel_launch(void* const* d_in, const int* in_sizes, int n_in,
                              void* d_out, int out_size, void* d_ws, size_t ws_size,
                              hipStream_t stream)
{
    const float* x         = (const float*)d_in[0];
    const float* edge_attr = (const float*)d_in[1];
    const float* gamma     = (const float*)d_in[2];
    const float* beta      = (const float*)d_in[3];
    const float* Wq        = (const float*)d_in[4];
    const float* Wk        = (const float*)d_in[5];
    const float* Wv        = (const float*)d_in[6];
    const float* Wo        = (const float*)d_in[7];
    const float* bo        = (const float*)d_in[8];
    const float* ea_w1     = (const float*)d_in[9];
    const float* ea_b1     = (const float*)d_in[10];
    const float* ea_w2     = (const float*)d_in[11];
    const float* ea_b2     = (const float*)d_in[12];
    const float* eg_w1     = (const float*)d_in[13];
    const float* eg_b1     = (const float*)d_in[14];
    const float* eg_w2     = (const float*)d_in[15];
    const float* eg_b2     = (const float*)d_in[16];
    const float* ln1_g     = (const float*)d_in[17];
    const float* ln1_b     = (const float*)d_in[18];
    const float* ln2_g     = (const float*)d_in[19];
    const float* ln2_b     = (const float*)d_in[20];
    const float* fw1       = (const float*)d_in[21];
    const float* fb1       = (const float*)d_in[22];
    const float* fw2       = (const float*)d_in[23];
    const float* fb2       = (const float*)d_in[24];
    const int*   ei        = (const int*)d_in[25];

    char* wsb = (char*)d_ws;
    size_t off = 0;
    auto alloc = [&](size_t bytes) { void* p = wsb + off; off += (bytes + 255) & ~(size_t)255; return p; };

    float* Qb     = (float*)alloc((size_t)N * HID * 4);
    float* Kb     = (float*)alloc((size_t)N * HID * 4);
    float* Vb     = (float*)alloc((size_t)N * HID * 4);
    float* logit  = (float*)alloc((size_t)E * NH * 4);
    float* marr   = (float*)alloc((size_t)N * NH * 4);
    float* rsarr  = (float*)alloc((size_t)N * NH * 4);
    float* aggb   = (float*)alloc((size_t)N * HID * 4);
    int*   cnt    = (int*)alloc((size_t)N * 4);
    int*   starts = (int*)alloc((size_t)(N + 1) * 4);
    int*   cursor = (int*)alloc((size_t)N * 4);
    int*   bsum   = (int*)alloc((size_t)NB * 4);
    int*   boff   = (int*)alloc((size_t)NB * 4);
    int*   perm   = (int*)alloc((size_t)E * 4);
    unsigned int*   wvb   = (unsigned int*)alloc((size_t)E * 64 * 4);
    unsigned short* fragW = (unsigned short*)alloc((size_t)18048 * 8 * 2);
    float* outp   = (float*)d_out;

    unsigned short* wqkv_f = fragW;                 // Wq|Wk|Wv at frag 0
    unsigned short* wo_f   = fragW + (size_t)6144  * 8;
    unsigned short* fw1_f  = fragW + (size_t)8192  * 8;
    unsigned short* fw2_f  = fragW + (size_t)12288 * 8;
    unsigned short* w1ea_f = fragW + (size_t)16384 * 8;
    unsigned short* w2ea_f = fragW + (size_t)16640 * 8;
    unsigned short* w1eg_f = fragW + (size_t)16768 * 8;
    unsigned short* w2eg_f = fragW + (size_t)17024 * 8;

    hipMemsetAsync(cnt, 0, (size_t)N * sizeof(int), stream);

    const int EB = (E + 255) / 256;
    const int NBLK = (N + 63) / 64;
    k_cvt<<<(18048 + 255) / 256, 256, 0, stream>>>(Wq, Wk, Wv, Wo, fw1, fw2,
                                                   ea_w1, ea_w2, eg_w1, eg_w2, fragW);
    k_ln_qkv_mfma<<<NBLK, 256, 0, stream>>>(x, ln1_g, ln1_b, wqkv_f, Qb, Kb, Vb);
    k_hist<<<EB, 256, 0, stream>>>(ei, cnt);
    k_bsum<<<NB, 256, 0, stream>>>(cnt, bsum);
    k_scan_b<<<1, 256, 0, stream>>>(bsum, boff);
    k_scan_final<<<NB, 256, 0, stream>>>(cnt, boff, starts, cursor);
    k_scatter<<<EB, 256, 0, stream>>>(ei, cursor, perm);
    k_logits_mfma<<<EB, 256, 0, stream>>>(edge_attr, ei, Qb, Kb,
                                          w1ea_f, ea_b1, w2ea_f, ea_b2, logit);
    k_softmax<<<(N * NH + 255) / 256, 256, 0, stream>>>(starts, perm, logit, marr, rsarr);
    k_weighted_mfma<<<EB, 256, 0, stream>>>(edge_attr, ei, Vb,
                                            w1eg_f, eg_b1, w2eg_f, eg_b2,
                                            logit, marr, rsarr, wvb);
    k_agg<<<(N + 3) / 4, 256, 0, stream>>>(starts, perm, wvb, aggb);
    k_node_out_mfma<<<NBLK, 256, 0, stream>>>(x, gamma, beta, wo_f, bo, ln2_g, ln2_b,
                                              fw1_f, fb1, fw2_f, fb2, aggb, outp);
}

// Round 6
// 612.186 us; speedup vs baseline: 7.4024x; 1.2023x over previous
//
#include <hip/hip_runtime.h>

constexpr int N   = 50000;
constexpr int E   = 500000;
constexpr int HID = 128;
constexpr int NH  = 8;
constexpr int ED  = 32;
constexpr int EGD = 64;
constexpr int NB  = (N + 255) / 256;

typedef short  bf16x8 __attribute__((ext_vector_type(8)));
typedef float  f32x4  __attribute__((ext_vector_type(4)));

__device__ __forceinline__ float gelu_f(float v) {
    return 0.5f * v * (1.f + erff(v * 0.70710678118654752f));
}
__device__ __forceinline__ float sigm_f(float v) {
    return 1.f / (1.f + __expf(-v));
}
__device__ __forceinline__ unsigned short f2bf(float f) {
    unsigned int u = __float_as_uint(f);
    return (unsigned short)((u + 0x7fffu + ((u >> 16) & 1u)) >> 16);
}
__device__ __forceinline__ float dot2(unsigned int a, unsigned int b) {
    float al = __uint_as_float(a << 16), ah = __uint_as_float(a & 0xffff0000u);
    float bl = __uint_as_float(b << 16), bh = __uint_as_float(b & 0xffff0000u);
    return al * bl + ah * bh;
}

// ---------------------------------------------------------------------------
// Weight conversion: all weight matrices -> bf16 MFMA B-fragment order.
// ---------------------------------------------------------------------------
__global__ __launch_bounds__(256) void k_cvt(
    const float* __restrict__ Wq, const float* __restrict__ Wk,
    const float* __restrict__ Wv, const float* __restrict__ Wo,
    const float* __restrict__ fw1, const float* __restrict__ fw2,
    const float* __restrict__ ea_w1, const float* __restrict__ ea_w2,
    const float* __restrict__ eg_w1, const float* __restrict__ eg_w2,
    unsigned short* __restrict__ dst)
{
    int f = blockIdx.x * 256 + threadIdx.x;
    if (f >= 18048) return;
    const float* W; int KT, srcN, base;
    if      (f < 2048)  { W = Wq;    KT = 4; srcN = 128; base = 0; }
    else if (f < 4096)  { W = Wk;    KT = 4; srcN = 128; base = 2048; }
    else if (f < 6144)  { W = Wv;    KT = 4; srcN = 128; base = 4096; }
    else if (f < 8192)  { W = Wo;    KT = 4; srcN = 128; base = 6144; }
    else if (f < 12288) { W = fw1;   KT = 4; srcN = 256; base = 8192; }
    else if (f < 16384) { W = fw2;   KT = 8; srcN = 128; base = 12288; }
    else if (f < 16640) { W = ea_w1; KT = 1; srcN = 64;  base = 16384; }
    else if (f < 16768) { W = ea_w2; KT = 2; srcN = 8;   base = 16640; }
    else if (f < 17024) { W = eg_w1; KT = 1; srcN = 64;  base = 16768; }
    else                { W = eg_w2; KT = 2; srcN = 128; base = 17024; }
    int fl = f - base, lane = fl & 63, t = fl >> 6;
    int ks = t % KT, nt = t / KT;
    int n  = nt * 16 + (lane & 15);
    int k0 = ks * 32 + (lane >> 4) * 8;
    union { unsigned short u[8]; uint4 v; } o;
#pragma unroll
    for (int j = 0; j < 8; j++)
        o.u[j] = (n < srcN) ? f2bf(W[(size_t)(k0 + j) * srcN + n]) : (unsigned short)0;
    *(uint4*)(dst + (size_t)f * 8) = o.v;
}

// ---------------------------------------------------------------------------
// LN1 + QKV via MFMA -> bf16 Q/K/V. 64 nodes per 256-thread block.
// ---------------------------------------------------------------------------
__global__ __launch_bounds__(256) void k_ln_qkv_mfma(
    const float* __restrict__ x, const float* __restrict__ g1, const float* __restrict__ b1,
    const unsigned short* __restrict__ wqkv,
    unsigned short* __restrict__ Q, unsigned short* __restrict__ K, unsigned short* __restrict__ V)
{
    __shared__ unsigned short xn_lds[64 * 128];
    const int tid = threadIdx.x;
    const int nodeBase = blockIdx.x * 64;

    {
        int nl = tid >> 2, q = tid & 3;
        int gn = nodeBase + nl; if (gn >= N) gn = N - 1;
        const float4* xp = (const float4*)(x + (size_t)gn * HID + q * 32);
        float xv[32]; float s = 0.f, ss = 0.f;
#pragma unroll
        for (int i = 0; i < 8; i++) {
            float4 t = xp[i];
            xv[4*i] = t.x; xv[4*i+1] = t.y; xv[4*i+2] = t.z; xv[4*i+3] = t.w;
        }
#pragma unroll
        for (int i = 0; i < 32; i++) { s += xv[i]; ss += xv[i] * xv[i]; }
        s += __shfl_xor(s, 1); ss += __shfl_xor(ss, 1);
        s += __shfl_xor(s, 2); ss += __shfl_xor(ss, 2);
        float mean = s * (1.f / HID);
        float ri = rsqrtf(ss * (1.f / HID) - mean * mean + 1e-5f);
#pragma unroll
        for (int j = 0; j < 4; j++) {
            union { unsigned short u[8]; uint4 v4; } o;
#pragma unroll
            for (int c = 0; c < 8; c++) {
                int col = q * 32 + j * 8 + c;
                o.u[c] = f2bf((xv[j*8+c] - mean) * ri * g1[col] + b1[col]);
            }
            int phys = (q * 4 + j) ^ (nl & 15);
            *(uint4*)&xn_lds[nl * 128 + phys * 8] = o.v4;
        }
    }
    __syncthreads();

    const int lane = tid & 63, w = tid >> 6, lm = lane & 15, kb = lane >> 4;
    bf16x8 af[4];
#pragma unroll
    for (int ks = 0; ks < 4; ks++)
        af[ks] = *(const bf16x8*)&xn_lds[(w * 16 + lm) * 128 + ((ks * 4 + kb) ^ lm) * 8];

    for (int nt = 0; nt < 24; nt++) {
        f32x4 c = {0.f, 0.f, 0.f, 0.f};
#pragma unroll
        for (int ks = 0; ks < 4; ks++)
            c = __builtin_amdgcn_mfma_f32_16x16x32_bf16(
                    af[ks], *(const bf16x8*)&wqkv[((size_t)(nt * 4 + ks) * 64 + lane) * 8],
                    c, 0, 0, 0);
        unsigned short* O = (nt < 8) ? Q : ((nt < 16) ? K : V);
        int cc = (nt & 7) * 16 + lm;
#pragma unroll
        for (int r = 0; r < 4; r++) {
            int node = nodeBase + w * 16 + kb * 4 + r;
            if (node < N) O[(size_t)node * HID + cc] = f2bf(c[r]);
        }
    }
}

// ---------------------------------------------------------------------------
// Sorting: histogram -> scan -> scatter (perm + srcj + dstj)
// ---------------------------------------------------------------------------
__global__ __launch_bounds__(256) void k_hist(const int* __restrict__ ei, int* __restrict__ cnt) {
    int e = blockIdx.x * 256 + threadIdx.x;
    if (e < E) atomicAdd(&cnt[ei[E + e]], 1);
}

__global__ __launch_bounds__(256) void k_bsum(const int* __restrict__ cnt, int* __restrict__ bsum) {
    int i = blockIdx.x * 256 + threadIdx.x;
    int v = (i < N) ? cnt[i] : 0;
#pragma unroll
    for (int m = 1; m < 64; m <<= 1) v += __shfl_xor(v, m);
    __shared__ int ws4[4];
    if ((threadIdx.x & 63) == 0) ws4[threadIdx.x >> 6] = v;
    __syncthreads();
    if (threadIdx.x == 0) bsum[blockIdx.x] = ws4[0] + ws4[1] + ws4[2] + ws4[3];
}

__global__ __launch_bounds__(256) void k_scan_b(const int* __restrict__ bsum, int* __restrict__ boff) {
    __shared__ int s[256];
    int t = threadIdx.x;
    int v = (t < NB) ? bsum[t] : 0;
    s[t] = v; __syncthreads();
    for (int off = 1; off < 256; off <<= 1) {
        int add = (t >= off) ? s[t - off] : 0;
        __syncthreads();
        s[t] += add;
        __syncthreads();
    }
    if (t < NB) boff[t] = s[t] - v;
}

__global__ __launch_bounds__(256) void k_scan_final(
    const int* __restrict__ cnt, const int* __restrict__ boff,
    int* __restrict__ starts, int* __restrict__ cursor)
{
    __shared__ int s[256];
    int t = threadIdx.x, i = blockIdx.x * 256 + t;
    int v = (i < N) ? cnt[i] : 0;
    s[t] = v; __syncthreads();
    for (int off = 1; off < 256; off <<= 1) {
        int add = (t >= off) ? s[t - off] : 0;
        __syncthreads();
        s[t] += add;
        __syncthreads();
    }
    int ex = boff[blockIdx.x] + s[t] - v;
    if (i < N) {
        starts[i] = ex;
        cursor[i] = ex;
        if (i == N - 1) starts[N] = ex + v;
    }
}

__global__ __launch_bounds__(256) void k_scatter(
    const int* __restrict__ ei, int* __restrict__ cursor,
    int* __restrict__ perm, int* __restrict__ srcj, int* __restrict__ dstj)
{
    int e = blockIdx.x * 256 + threadIdx.x;
    if (e < E) {
        int src = ei[e], dst = ei[E + e];
        int p = atomicAdd(&cursor[dst], 1);
        perm[p] = e;
        srcj[p] = src;
        dstj[p] = dst;
    }
}

// ---------------------------------------------------------------------------
// Edge-MLP logits in dst-sorted order -> logit_s[j][8].
// ---------------------------------------------------------------------------
__global__ __launch_bounds__(256) void k_logits_s(
    const float* __restrict__ edge_attr, const int* __restrict__ perm,
    const int* __restrict__ srcj, const int* __restrict__ dstj,
    const unsigned short* __restrict__ Qb, const unsigned short* __restrict__ Kb,
    const unsigned short* __restrict__ w1b, const float* __restrict__ b1,
    const unsigned short* __restrict__ w2b, const float* __restrict__ b2,
    float* __restrict__ logit_s)
{
    __shared__ unsigned short ea_lds[256 * 32];   // 16KB; aliased as st16 after GEMM1
    __shared__ unsigned short hid_lds[256 * 64];  // 32KB
    __shared__ int perm_lds[256];
    float* st16 = (float*)ea_lds;                 // row-disjoint with per-wave ea rows

    const int tid = threadIdx.x;
    const int jBase = blockIdx.x * 256;
    const int lane = tid & 63;
    const int wv = tid >> 6;
    const int wBase = wv * 64;
    const int lm = lane & 15;
    const int kb = lane >> 4;
    const int rowq = kb * 4;

    {
        int j = jBase + tid;
        perm_lds[tid] = perm[(j < E) ? j : (E - 1)];
    }
    __syncthreads();

#pragma unroll
    for (int it = 0; it < 8; it++) {
        int idx = it * 256 + tid;
        int el = idx >> 3, c = (idx & 7) * 4;
        int ge = perm_lds[el];
        float4 v = *(const float4*)(edge_attr + (size_t)ge * ED + c);
        int g = ((c >> 3) ^ (el & 3));
        unsigned short* p = &ea_lds[el * 32 + g * 8 + (c & 7)];
        p[0] = f2bf(v.x); p[1] = f2bf(v.y); p[2] = f2bf(v.z); p[3] = f2bf(v.w);
    }
    __syncthreads();

    // GEMM1
    bf16x8 a1[4];
#pragma unroll
    for (int mt = 0; mt < 4; mt++) {
        int m = wBase + mt * 16 + lm;
        a1[mt] = *(const bf16x8*)&ea_lds[m * 32 + (kb ^ (m & 3)) * 8];
    }
    f32x4 acc1[4][4];
#pragma unroll
    for (int mt = 0; mt < 4; mt++)
#pragma unroll
        for (int nt = 0; nt < 4; nt++) {
            f32x4 z = {0.f, 0.f, 0.f, 0.f};
            acc1[mt][nt] = __builtin_amdgcn_mfma_f32_16x16x32_bf16(
                a1[mt], *(const bf16x8*)&w1b[(nt * 64 + lane) * 8], z, 0, 0, 0);
        }
#pragma unroll
    for (int nt = 0; nt < 4; nt++) {
        float bias = b1[nt * 16 + lm];
#pragma unroll
        for (int mt = 0; mt < 4; mt++)
#pragma unroll
            for (int r = 0; r < 4; r++) {
                int row = wBase + mt * 16 + rowq + r;
                int col = nt * 16 + lm;
                int g = (col >> 3) ^ (row & 7);
                hid_lds[row * 64 + g * 8 + (col & 7)] = f2bf(gelu_f(acc1[mt][nt][r] + bias));
            }
    }

    // GEMM2 (own-wave rows; no barrier needed)
    bf16x8 a2[4][2];
#pragma unroll
    for (int mt = 0; mt < 4; mt++)
#pragma unroll
        for (int ks = 0; ks < 2; ks++) {
            int m = wBase + mt * 16 + lm;
            int g = (ks * 4 + kb) ^ (m & 7);
            a2[mt][ks] = *(const bf16x8*)&hid_lds[m * 64 + g * 8];
        }
    {
        float bias = b2[lm & 7];
#pragma unroll
        for (int mt = 0; mt < 4; mt++) {
            f32x4 acc = {bias, bias, bias, bias};
            acc = __builtin_amdgcn_mfma_f32_16x16x32_bf16(
                a2[mt][0], *(const bf16x8*)&w2b[(0 * 64 + lane) * 8], acc, 0, 0, 0);
            acc = __builtin_amdgcn_mfma_f32_16x16x32_bf16(
                a2[mt][1], *(const bf16x8*)&w2b[(1 * 64 + lane) * 8], acc, 0, 0, 0);
            if (lm < 8) {
#pragma unroll
                for (int r = 0; r < 4; r++)
                    st16[(wBase + mt * 16 + rowq + r) * 16 + lm] = acc[r];
            }
        }
    }
    __syncthreads();

    // epilogue: += 0.25 * Q[dst].K[src] (bf16 rows), store logit_s[j]
    int j = jBase + tid;
    if (j < E) {
        int src = srcj[j], dst = dstj[j];
        const uint4* qp = (const uint4*)(Qb + (size_t)dst * HID);
        const uint4* kp = (const uint4*)(Kb + (size_t)src * HID);
        float lg[8];
#pragma unroll
        for (int h = 0; h < 8; h++) {
            float dot = 0.f;
#pragma unroll
            for (int t = 0; t < 2; t++) {
                uint4 q = qp[h * 2 + t], k4 = kp[h * 2 + t];
                dot += dot2(q.x, k4.x) + dot2(q.y, k4.y) + dot2(q.z, k4.z) + dot2(q.w, k4.w);
            }
            lg[h] = st16[tid * 16 + h] + 0.25f * dot;
        }
        float4* op = (float4*)(logit_s + (size_t)j * NH);
        op[0] = make_float4(lg[0], lg[1], lg[2], lg[3]);
        op[1] = make_float4(lg[4], lg[5], lg[6], lg[7]);
    }
}

// ---------------------------------------------------------------------------
// Segment softmax; overwrites logit_s with final attention weights.
// ---------------------------------------------------------------------------
__global__ __launch_bounds__(256) void k_softmax_s(
    const int* __restrict__ starts, float* __restrict__ logit_s)
{
    int i = blockIdx.x * 256 + threadIdx.x;
    if (i >= N * NH) return;
    int dst = i >> 3, h = i & 7;
    int s0 = starts[dst], s1 = starts[dst + 1];
    float m = 0.f;
    for (int j = s0; j < s1; j++)
        m = fmaxf(m, logit_s[(size_t)j * NH + h]);
    float s = 0.f;
    for (int j = s0; j < s1; j++)
        s += __expf(logit_s[(size_t)j * NH + h] - m);
    float rs = 1.f / (s + 1e-10f);
    for (int j = s0; j < s1; j++) {
        size_t idx = (size_t)j * NH + h;
        logit_s[idx] = __expf(logit_s[idx] - m) * rs;
    }
}

// ---------------------------------------------------------------------------
// Gate MLP (both GEMMs) + attn*sigmoid(gate)*V[src] -> wout[j][128] bf16,
// all in dst-sorted order.
// ---------------------------------------------------------------------------
__global__ __launch_bounds__(256) void k_weighted_s(
    const float* __restrict__ edge_attr, const int* __restrict__ perm,
    const int* __restrict__ srcj, const unsigned short* __restrict__ Vb,
    const unsigned short* __restrict__ w1b, const float* __restrict__ b1,
    const unsigned short* __restrict__ w2b, const float* __restrict__ b2,
    const float* __restrict__ attn_s, unsigned int* __restrict__ wout)
{
    __shared__ unsigned short ea_lds[256 * 32];   // staging, then wout stage
    __shared__ unsigned short hid_lds[256 * 64];
    __shared__ float attn_lds[256 * 8];
    __shared__ int src_lds[256];
    __shared__ int perm_lds[256];

    const int tid = threadIdx.x;
    const int jBase = blockIdx.x * 256;
    const int lane = tid & 63;
    const int wv = tid >> 6;
    const int wBase = wv * 64;
    const int lm = lane & 15;
    const int kb = lane >> 4;
    const int rowq = kb * 4;

    {
        int j = jBase + tid; if (j >= E) j = E - 1;
        perm_lds[tid] = perm[j];
        src_lds[tid] = srcj[j];
        const float4* ap = (const float4*)(attn_s + (size_t)j * NH);
        *(float4*)&attn_lds[tid * 8 + 0] = ap[0];
        *(float4*)&attn_lds[tid * 8 + 4] = ap[1];
    }
    __syncthreads();

#pragma unroll
    for (int it = 0; it < 8; it++) {
        int idx = it * 256 + tid;
        int el = idx >> 3, c = (idx & 7) * 4;
        int ge = perm_lds[el];
        float4 v = *(const float4*)(edge_attr + (size_t)ge * ED + c);
        int g = ((c >> 3) ^ (el & 3));
        unsigned short* p = &ea_lds[el * 32 + g * 8 + (c & 7)];
        p[0] = f2bf(v.x); p[1] = f2bf(v.y); p[2] = f2bf(v.z); p[3] = f2bf(v.w);
    }
    __syncthreads();

    // GEMM1
    bf16x8 a1[4];
#pragma unroll
    for (int mt = 0; mt < 4; mt++) {
        int m = wBase + mt * 16 + lm;
        a1[mt] = *(const bf16x8*)&ea_lds[m * 32 + (kb ^ (m & 3)) * 8];
    }
    f32x4 acc1[4][4];
#pragma unroll
    for (int mt = 0; mt < 4; mt++)
#pragma unroll
        for (int nt = 0; nt < 4; nt++) {
            f32x4 z = {0.f, 0.f, 0.f, 0.f};
            acc1[mt][nt] = __builtin_amdgcn_mfma_f32_16x16x32_bf16(
                a1[mt], *(const bf16x8*)&w1b[(nt * 64 + lane) * 8], z, 0, 0, 0);
        }
#pragma unroll
    for (int nt = 0; nt < 4; nt++) {
        float bias = b1[nt * 16 + lm];
#pragma unroll
        for (int mt = 0; mt < 4; mt++)
#pragma unroll
            for (int r = 0; r < 4; r++) {
                int row = wBase + mt * 16 + rowq + r;
                int col = nt * 16 + lm;
                int g = (col >> 3) ^ (row & 7);
                hid_lds[row * 64 + g * 8 + (col & 7)] = f2bf(gelu_f(acc1[mt][nt][r] + bias));
            }
    }

    bf16x8 a2[4][2];
#pragma unroll
    for (int mt = 0; mt < 4; mt++)
#pragma unroll
        for (int ks = 0; ks < 2; ks++) {
            int m = wBase + mt * 16 + lm;
            int g = (ks * 4 + kb) ^ (m & 7);
            a2[mt][ks] = *(const bf16x8*)&hid_lds[m * 64 + g * 8];
        }

#pragma unroll 1
    for (int ch = 0; ch < 4; ch++) {
        const int cc = ch * 32;
        f32x4 acc[4][2];
#pragma unroll
        for (int nt = 0; nt < 2; nt++) {
            float bias = b2[cc + nt * 16 + lm];
            const bf16x8 bf0 = *(const bf16x8*)&w2b[(((ch * 2 + nt) * 2 + 0) * 64 + lane) * 8];
            const bf16x8 bf1 = *(const bf16x8*)&w2b[(((ch * 2 + nt) * 2 + 1) * 64 + lane) * 8];
#pragma unroll
            for (int mt = 0; mt < 4; mt++) {
                f32x4 c = {bias, bias, bias, bias};
                c = __builtin_amdgcn_mfma_f32_16x16x32_bf16(a2[mt][0], bf0, c, 0, 0, 0);
                c = __builtin_amdgcn_mfma_f32_16x16x32_bf16(a2[mt][1], bf1, c, 0, 0, 0);
                acc[mt][nt] = c;
            }
        }
        __syncthreads();   // all waves done with ea_lds (a1) / previous chunk's coop reads
#pragma unroll
        for (int nt = 0; nt < 2; nt++) {
            int head = ch * 2 + nt;
#pragma unroll
            for (int mt = 0; mt < 4; mt++)
#pragma unroll
                for (int r = 0; r < 4; r++) {
                    int em = wBase + mt * 16 + rowq + r;
                    float a = attn_lds[em * 8 + head];
                    int src = src_lds[em];
                    float vval = __uint_as_float(
                        ((unsigned int)Vb[(size_t)src * HID + cc + nt * 16 + lm]) << 16);
                    float w = a * sigm_f(acc[mt][nt][r]) * vval;
                    int cl = nt * 16 + lm;
                    int g = (cl >> 3) ^ (em & 3);
                    ea_lds[em * 32 + g * 8 + (cl & 7)] = f2bf(w);
                }
        }
        __syncthreads();
#pragma unroll
        for (int it = 0; it < 4; it++) {
            int idx = it * 256 + tid;
            int el = idx >> 2, q = idx & 3;
            if (jBase + el < E) {
                int g = q ^ (el & 3);
                uint4 u = *(const uint4*)&ea_lds[el * 32 + g * 8];
                *(uint4*)(wout + (size_t)(jBase + el) * 64 + ch * 16 + q * 4) = u;
            }
        }
    }
}

// ---------------------------------------------------------------------------
// Streaming segment-sum of weighted rows (sorted order). One wave per dst.
// ---------------------------------------------------------------------------
__global__ __launch_bounds__(256) void k_agg(
    const int* __restrict__ starts, const unsigned int* __restrict__ wv,
    float* __restrict__ agg)
{
    int wave = threadIdx.x >> 6, lane = threadIdx.x & 63;
    int dst = blockIdx.x * 4 + wave;
    if (dst >= N) return;
    int s0 = starts[dst], s1 = starts[dst + 1];
    float ax = 0.f, ay = 0.f;
    for (int j = s0; j < s1; j++) {
        unsigned int u = wv[(size_t)j * 64 + lane];
        ax += __uint_as_float(u << 16);
        ay += __uint_as_float(u & 0xffff0000u);
    }
    float2* o = (float2*)(agg + (size_t)dst * HID + lane * 2);
    *o = make_float2(ax, ay);
}

// ---------------------------------------------------------------------------
// Node epilogue via MFMA.
// ---------------------------------------------------------------------------
__global__ __launch_bounds__(256) void k_node_out_mfma(
    const float* __restrict__ x, const float* __restrict__ gamma, const float* __restrict__ beta,
    const unsigned short* __restrict__ wo_f, const float* __restrict__ bo,
    const float* __restrict__ g2, const float* __restrict__ b2,
    const unsigned short* __restrict__ fw1_f, const float* __restrict__ fb1,
    const unsigned short* __restrict__ fw2_f, const float* __restrict__ fb2,
    const float* __restrict__ agg, float* __restrict__ out)
{
    __shared__ unsigned short a_lds[64 * 128];
    __shared__ unsigned short f1_lds[64 * 256];
    const int tid = threadIdx.x;
    const int nodeBase = blockIdx.x * 64;

    {
        int nl = tid >> 2, q = tid & 3;
        int gn = nodeBase + nl; if (gn >= N) gn = N - 1;
        const float4* ap = (const float4*)(agg + (size_t)gn * HID + q * 32);
#pragma unroll
        for (int j = 0; j < 4; j++) {
            float4 t0 = ap[2 * j], t1 = ap[2 * j + 1];
            union { unsigned short u[8]; uint4 v4; } o;
            o.u[0] = f2bf(t0.x); o.u[1] = f2bf(t0.y); o.u[2] = f2bf(t0.z); o.u[3] = f2bf(t0.w);
            o.u[4] = f2bf(t1.x); o.u[5] = f2bf(t1.y); o.u[6] = f2bf(t1.z); o.u[7] = f2bf(t1.w);
            int phys = (q * 4 + j) ^ (nl & 15);
            *(uint4*)&a_lds[nl * 128 + phys * 8] = o.v4;
        }
    }
    __syncthreads();

    const int lane = tid & 63, w = tid >> 6, lm = lane & 15, kb = lane >> 4;
    const int rowLoc = w * 16;

    f32x4 xo[8];
    {
        bf16x8 af[4];
#pragma unroll
        for (int ks = 0; ks < 4; ks++)
            af[ks] = *(const bf16x8*)&a_lds[(rowLoc + lm) * 128 + ((ks * 4 + kb) ^ lm) * 8];
#pragma unroll
        for (int nt = 0; nt < 8; nt++) {
            f32x4 c = {0.f, 0.f, 0.f, 0.f};
#pragma unroll
            for (int ks = 0; ks < 4; ks++)
                c = __builtin_amdgcn_mfma_f32_16x16x32_bf16(
                        af[ks], *(const bf16x8*)&wo_f[((size_t)(nt * 4 + ks) * 64 + lane) * 8],
                        c, 0, 0, 0);
            xo[nt] = c;
        }
    }

    float x1v[8][4];
#pragma unroll
    for (int nt = 0; nt < 8; nt++) {
        int col = nt * 16 + lm;
        float boc = bo[col];
#pragma unroll
        for (int r = 0; r < 4; r++) {
            int node = nodeBase + rowLoc + kb * 4 + r; if (node >= N) node = N - 1;
            size_t idx = (size_t)node * HID + col;
            x1v[nt][r] = x[idx] + gamma[idx] * (xo[nt][r] + boc) + beta[idx];
        }
    }

    float s4[4] = {0,0,0,0}, q4[4] = {0,0,0,0};
#pragma unroll
    for (int nt = 0; nt < 8; nt++)
#pragma unroll
        for (int r = 0; r < 4; r++) { s4[r] += x1v[nt][r]; q4[r] += x1v[nt][r] * x1v[nt][r]; }
#pragma unroll
    for (int m = 1; m < 16; m <<= 1)
#pragma unroll
        for (int r = 0; r < 4; r++) { s4[r] += __shfl_xor(s4[r], m); q4[r] += __shfl_xor(q4[r], m); }
    float mu4[4], ri4[4];
#pragma unroll
    for (int r = 0; r < 4; r++) {
        float mu = s4[r] * (1.f / HID);
        mu4[r] = mu;
        ri4[r] = rsqrtf(q4[r] * (1.f / HID) - mu * mu + 1e-5f);
    }

#pragma unroll
    for (int nt = 0; nt < 8; nt++) {
        int col = nt * 16 + lm;
        float g2c = g2[col], b2c = b2[col];
#pragma unroll
        for (int r = 0; r < 4; r++) {
            float xn = (x1v[nt][r] - mu4[r]) * ri4[r] * g2c + b2c;
            int row = rowLoc + kb * 4 + r;
            int g = col >> 3;
            a_lds[row * 128 + (g ^ (row & 15)) * 8 + (col & 7)] = f2bf(xn);
        }
    }
    __syncthreads();

    {
        bf16x8 af[4];
#pragma unroll
        for (int ks = 0; ks < 4; ks++)
            af[ks] = *(const bf16x8*)&a_lds[(rowLoc + lm) * 128 + ((ks * 4 + kb) ^ lm) * 8];
#pragma unroll
        for (int nt = 0; nt < 16; nt++) {
            f32x4 c = {0.f, 0.f, 0.f, 0.f};
#pragma unroll
            for (int ks = 0; ks < 4; ks++)
                c = __builtin_amdgcn_mfma_f32_16x16x32_bf16(
                        af[ks], *(const bf16x8*)&fw1_f[((size_t)(nt * 4 + ks) * 64 + lane) * 8],
                        c, 0, 0, 0);
            int col = nt * 16 + lm;
            float fbc = fb1[col];
#pragma unroll
            for (int r = 0; r < 4; r++) {
                int row = rowLoc + kb * 4 + r;
                int g = col >> 3;
                int phys = (g & 16) | ((g ^ (row & 15)) & 15);
                f1_lds[row * 256 + phys * 8 + (col & 7)] = f2bf(gelu_f(c[r] + fbc));
            }
        }
    }
    __syncthreads();

    {
        bf16x8 af[8];
#pragma unroll
        for (int ks = 0; ks < 8; ks++) {
            int g = ks * 4 + kb;
            int phys = (g & 16) | ((g ^ lm) & 15);
            af[ks] = *(const bf16x8*)&f1_lds[(rowLoc + lm) * 256 + phys * 8];
        }
#pragma unroll
        for (int nt = 0; nt < 8; nt++) {
            f32x4 c = {0.f, 0.f, 0.f, 0.f};
#pragma unroll
            for (int ks = 0; ks < 8; ks++)
                c = __builtin_amdgcn_mfma_f32_16x16x32_bf16(
                        af[ks], *(const bf16x8*)&fw2_f[((size_t)(nt * 8 + ks) * 64 + lane) * 8],
                        c, 0, 0, 0);
            int col = nt * 16 + lm;
            float fbc = fb2[col];
#pragma unroll
            for (int r = 0; r < 4; r++) {
                int node = nodeBase + rowLoc + kb * 4 + r;
                if (node < N) out[(size_t)node * HID + col] = x1v[nt][r] + c[r] + fbc;
            }
        }
    }
}

// ---------------------------------------------------------------------------
extern "C" void kernel_launch(void* const* d_in, const int* in_sizes, int n_in,
                              void* d_out, int out_size, void* d_ws, size_t ws_size,
                              hipStream_t stream)
{
    const float* x         = (const float*)d_in[0];
    const float* edge_attr = (const float*)d_in[1];
    const float* gamma     = (const float*)d_in[2];
    const float* beta      = (const float*)d_in[3];
    const float* Wq        = (const float*)d_in[4];
    const float* Wk        = (const float*)d_in[5];
    const float* Wv        = (const float*)d_in[6];
    const float* Wo        = (const float*)d_in[7];
    const float* bo        = (const float*)d_in[8];
    const float* ea_w1     = (const float*)d_in[9];
    const float* ea_b1     = (const float*)d_in[10];
    const float* ea_w2     = (const float*)d_in[11];
    const float* ea_b2     = (const float*)d_in[12];
    const float* eg_w1     = (const float*)d_in[13];
    const float* eg_b1     = (const float*)d_in[14];
    const float* eg_w2     = (const float*)d_in[15];
    const float* eg_b2     = (const float*)d_in[16];
    const float* ln1_g     = (const float*)d_in[17];
    const float* ln1_b     = (const float*)d_in[18];
    const float* ln2_g     = (const float*)d_in[19];
    const float* ln2_b     = (const float*)d_in[20];
    const float* fw1       = (const float*)d_in[21];
    const float* fb1       = (const float*)d_in[22];
    const float* fw2       = (const float*)d_in[23];
    const float* fb2       = (const float*)d_in[24];
    const int*   ei        = (const int*)d_in[25];

    char* wsb = (char*)d_ws;
    size_t off = 0;
    auto alloc = [&](size_t bytes) { void* p = wsb + off; off += (bytes + 255) & ~(size_t)255; return p; };

    unsigned short* Qb = (unsigned short*)alloc((size_t)N * HID * 2);
    unsigned short* Kb = (unsigned short*)alloc((size_t)N * HID * 2);
    unsigned short* Vb = (unsigned short*)alloc((size_t)N * HID * 2);
    float* logit_s = (float*)alloc((size_t)E * NH * 4);
    float* aggb    = (float*)alloc((size_t)N * HID * 4);
    int*   cnt     = (int*)alloc((size_t)N * 4);
    int*   starts  = (int*)alloc((size_t)(N + 1) * 4);
    int*   cursor  = (int*)alloc((size_t)N * 4);
    int*   bsum    = (int*)alloc((size_t)NB * 4);
    int*   boff    = (int*)alloc((size_t)NB * 4);
    int*   perm    = (int*)alloc((size_t)E * 4);
    int*   srcj    = (int*)alloc((size_t)E * 4);
    int*   dstj    = (int*)alloc((size_t)E * 4);
    unsigned int*   wvb   = (unsigned int*)alloc((size_t)E * 64 * 4);
    unsigned short* fragW = (unsigned short*)alloc((size_t)18048 * 8 * 2);
    float* outp = (float*)d_out;

    unsigned short* wqkv_f = fragW;
    unsigned short* wo_f   = fragW + (size_t)6144  * 8;
    unsigned short* fw1_f  = fragW + (size_t)8192  * 8;
    unsigned short* fw2_f  = fragW + (size_t)12288 * 8;
    unsigned short* w1ea_f = fragW + (size_t)16384 * 8;
    unsigned short* w2ea_f = fragW + (size_t)16640 * 8;
    unsigned short* w1eg_f = fragW + (size_t)16768 * 8;
    unsigned short* w2eg_f = fragW + (size_t)17024 * 8;

    hipMemsetAsync(cnt, 0, (size_t)N * sizeof(int), stream);

    const int EB = (E + 255) / 256;
    const int NBLK = (N + 63) / 64;
    k_cvt<<<(18048 + 255) / 256, 256, 0, stream>>>(Wq, Wk, Wv, Wo, fw1, fw2,
                                                   ea_w1, ea_w2, eg_w1, eg_w2, fragW);
    k_ln_qkv_mfma<<<NBLK, 256, 0, stream>>>(x, ln1_g, ln1_b, wqkv_f, Qb, Kb, Vb);
    k_hist<<<EB, 256, 0, stream>>>(ei, cnt);
    k_bsum<<<NB, 256, 0, stream>>>(cnt, bsum);
    k_scan_b<<<1, 256, 0, stream>>>(bsum, boff);
    k_scan_final<<<NB, 256, 0, stream>>>(cnt, boff, starts, cursor);
    k_scatter<<<EB, 256, 0, stream>>>(ei, cursor, perm, srcj, dstj);
    k_logits_s<<<EB, 256, 0, stream>>>(edge_attr, perm, srcj, dstj, Qb, Kb,
                                       w1ea_f, ea_b1, w2ea_f, ea_b2, logit_s);
    k_softmax_s<<<(N * NH + 255) / 256, 256, 0, stream>>>(starts, logit_s);
    k_weighted_s<<<EB, 256, 0, stream>>>(edge_attr, perm, srcj, Vb,
                                         w1eg_f, eg_b1, w2eg_f, eg_b2, logit_s, wvb);
    k_agg<<<(N + 3) / 4, 256, 0, stream>>>(starts, wvb, aggb);
    k_node_out_mfma<<<NBLK, 256, 0, stream>>>(x, gamma, beta, wo_f, bo, ln2_g, ln2_b,
                                              fw1_f, fb1, fw2_f, fb2, aggb, outp);
}

// Round 7
// 586.811 us; speedup vs baseline: 7.7225x; 1.0432x over previous
//
#include <hip/hip_runtime.h>

constexpr int N   = 50000;
constexpr int E   = 500000;
constexpr int HID = 128;
constexpr int NH  = 8;
constexpr int ED  = 32;
constexpr int EGD = 64;
constexpr int NB  = (N + 255) / 256;

typedef short  bf16x8 __attribute__((ext_vector_type(8)));
typedef float  f32x4  __attribute__((ext_vector_type(4)));

__device__ __forceinline__ float gelu_f(float v) {
    return 0.5f * v * (1.f + erff(v * 0.70710678118654752f));
}
__device__ __forceinline__ float sigm_f(float v) {
    return 1.f / (1.f + __expf(-v));
}
__device__ __forceinline__ unsigned short f2bf(float f) {
    unsigned int u = __float_as_uint(f);
    return (unsigned short)((u + 0x7fffu + ((u >> 16) & 1u)) >> 16);
}
__device__ __forceinline__ float dot2(unsigned int a, unsigned int b) {
    float al = __uint_as_float(a << 16), ah = __uint_as_float(a & 0xffff0000u);
    float bl = __uint_as_float(b << 16), bh = __uint_as_float(b & 0xffff0000u);
    return al * bl + ah * bh;
}

// ---------------------------------------------------------------------------
// Weight conversion: all weight matrices -> bf16 MFMA B-fragment order.
// ---------------------------------------------------------------------------
__global__ __launch_bounds__(256) void k_cvt(
    const float* __restrict__ Wq, const float* __restrict__ Wk,
    const float* __restrict__ Wv, const float* __restrict__ Wo,
    const float* __restrict__ fw1, const float* __restrict__ fw2,
    const float* __restrict__ ea_w1, const float* __restrict__ ea_w2,
    const float* __restrict__ eg_w1, const float* __restrict__ eg_w2,
    unsigned short* __restrict__ dst)
{
    int f = blockIdx.x * 256 + threadIdx.x;
    if (f >= 18048) return;
    const float* W; int KT, srcN, base;
    if      (f < 2048)  { W = Wq;    KT = 4; srcN = 128; base = 0; }
    else if (f < 4096)  { W = Wk;    KT = 4; srcN = 128; base = 2048; }
    else if (f < 6144)  { W = Wv;    KT = 4; srcN = 128; base = 4096; }
    else if (f < 8192)  { W = Wo;    KT = 4; srcN = 128; base = 6144; }
    else if (f < 12288) { W = fw1;   KT = 4; srcN = 256; base = 8192; }
    else if (f < 16384) { W = fw2;   KT = 8; srcN = 128; base = 12288; }
    else if (f < 16640) { W = ea_w1; KT = 1; srcN = 64;  base = 16384; }
    else if (f < 16768) { W = ea_w2; KT = 2; srcN = 8;   base = 16640; }
    else if (f < 17024) { W = eg_w1; KT = 1; srcN = 64;  base = 16768; }
    else                { W = eg_w2; KT = 2; srcN = 128; base = 17024; }
    int fl = f - base, lane = fl & 63, t = fl >> 6;
    int ks = t % KT, nt = t / KT;
    int n  = nt * 16 + (lane & 15);
    int k0 = ks * 32 + (lane >> 4) * 8;
    union { unsigned short u[8]; uint4 v; } o;
#pragma unroll
    for (int j = 0; j < 8; j++)
        o.u[j] = (n < srcN) ? f2bf(W[(size_t)(k0 + j) * srcN + n]) : (unsigned short)0;
    *(uint4*)(dst + (size_t)f * 8) = o.v;
}

// ---------------------------------------------------------------------------
// LN1 + QKV via MFMA -> bf16 Q/K/V. 64 nodes per 256-thread block.
// ---------------------------------------------------------------------------
__global__ __launch_bounds__(256) void k_ln_qkv_mfma(
    const float* __restrict__ x, const float* __restrict__ g1, const float* __restrict__ b1,
    const unsigned short* __restrict__ wqkv,
    unsigned short* __restrict__ Q, unsigned short* __restrict__ K, unsigned short* __restrict__ V)
{
    __shared__ unsigned short xn_lds[64 * 128];
    const int tid = threadIdx.x;
    const int nodeBase = blockIdx.x * 64;

    {
        int nl = tid >> 2, q = tid & 3;
        int gn = nodeBase + nl; if (gn >= N) gn = N - 1;
        const float4* xp = (const float4*)(x + (size_t)gn * HID + q * 32);
        float xv[32]; float s = 0.f, ss = 0.f;
#pragma unroll
        for (int i = 0; i < 8; i++) {
            float4 t = xp[i];
            xv[4*i] = t.x; xv[4*i+1] = t.y; xv[4*i+2] = t.z; xv[4*i+3] = t.w;
        }
#pragma unroll
        for (int i = 0; i < 32; i++) { s += xv[i]; ss += xv[i] * xv[i]; }
        s += __shfl_xor(s, 1); ss += __shfl_xor(ss, 1);
        s += __shfl_xor(s, 2); ss += __shfl_xor(ss, 2);
        float mean = s * (1.f / HID);
        float ri = rsqrtf(ss * (1.f / HID) - mean * mean + 1e-5f);
#pragma unroll
        for (int j = 0; j < 4; j++) {
            union { unsigned short u[8]; uint4 v4; } o;
#pragma unroll
            for (int c = 0; c < 8; c++) {
                int col = q * 32 + j * 8 + c;
                o.u[c] = f2bf((xv[j*8+c] - mean) * ri * g1[col] + b1[col]);
            }
            int phys = (q * 4 + j) ^ (nl & 15);
            *(uint4*)&xn_lds[nl * 128 + phys * 8] = o.v4;
        }
    }
    __syncthreads();

    const int lane = tid & 63, w = tid >> 6, lm = lane & 15, kb = lane >> 4;
    bf16x8 af[4];
#pragma unroll
    for (int ks = 0; ks < 4; ks++)
        af[ks] = *(const bf16x8*)&xn_lds[(w * 16 + lm) * 128 + ((ks * 4 + kb) ^ lm) * 8];

    for (int nt = 0; nt < 24; nt++) {
        f32x4 c = {0.f, 0.f, 0.f, 0.f};
#pragma unroll
        for (int ks = 0; ks < 4; ks++)
            c = __builtin_amdgcn_mfma_f32_16x16x32_bf16(
                    af[ks], *(const bf16x8*)&wqkv[((size_t)(nt * 4 + ks) * 64 + lane) * 8],
                    c, 0, 0, 0);
        unsigned short* O = (nt < 8) ? Q : ((nt < 16) ? K : V);
        int cc = (nt & 7) * 16 + lm;
#pragma unroll
        for (int r = 0; r < 4; r++) {
            int node = nodeBase + w * 16 + kb * 4 + r;
            if (node < N) O[(size_t)node * HID + cc] = f2bf(c[r]);
        }
    }
}

// ---------------------------------------------------------------------------
// Sorting: histogram -> scan -> scatter (perm + srcj + dstj)
// ---------------------------------------------------------------------------
__global__ __launch_bounds__(256) void k_hist(const int* __restrict__ ei, int* __restrict__ cnt) {
    int e = blockIdx.x * 256 + threadIdx.x;
    if (e < E) atomicAdd(&cnt[ei[E + e]], 1);
}

__global__ __launch_bounds__(256) void k_bsum(const int* __restrict__ cnt, int* __restrict__ bsum) {
    int i = blockIdx.x * 256 + threadIdx.x;
    int v = (i < N) ? cnt[i] : 0;
#pragma unroll
    for (int m = 1; m < 64; m <<= 1) v += __shfl_xor(v, m);
    __shared__ int ws4[4];
    if ((threadIdx.x & 63) == 0) ws4[threadIdx.x >> 6] = v;
    __syncthreads();
    if (threadIdx.x == 0) bsum[blockIdx.x] = ws4[0] + ws4[1] + ws4[2] + ws4[3];
}

__global__ __launch_bounds__(256) void k_scan_b(const int* __restrict__ bsum, int* __restrict__ boff) {
    __shared__ int s[256];
    int t = threadIdx.x;
    int v = (t < NB) ? bsum[t] : 0;
    s[t] = v; __syncthreads();
    for (int off = 1; off < 256; off <<= 1) {
        int add = (t >= off) ? s[t - off] : 0;
        __syncthreads();
        s[t] += add;
        __syncthreads();
    }
    if (t < NB) boff[t] = s[t] - v;
}

__global__ __launch_bounds__(256) void k_scan_final(
    const int* __restrict__ cnt, const int* __restrict__ boff,
    int* __restrict__ starts, int* __restrict__ cursor)
{
    __shared__ int s[256];
    int t = threadIdx.x, i = blockIdx.x * 256 + t;
    int v = (i < N) ? cnt[i] : 0;
    s[t] = v; __syncthreads();
    for (int off = 1; off < 256; off <<= 1) {
        int add = (t >= off) ? s[t - off] : 0;
        __syncthreads();
        s[t] += add;
        __syncthreads();
    }
    int ex = boff[blockIdx.x] + s[t] - v;
    if (i < N) {
        starts[i] = ex;
        cursor[i] = ex;
        if (i == N - 1) starts[N] = ex + v;
    }
}

__global__ __launch_bounds__(256) void k_scatter(
    const int* __restrict__ ei, int* __restrict__ cursor,
    int* __restrict__ perm, int* __restrict__ srcj, int* __restrict__ dstj)
{
    int e = blockIdx.x * 256 + threadIdx.x;
    if (e < E) {
        int src = ei[e], dst = ei[E + e];
        int p = atomicAdd(&cursor[dst], 1);
        perm[p] = e;
        srcj[p] = src;
        dstj[p] = dst;
    }
}

// ---------------------------------------------------------------------------
// Fused edge kernel (dst-sorted order):
//   logits = gelu(ea@w1ea+b1ea)@w2ea + b2ea + 0.25*Q[dst].K[src] -> logit_s
//   gv     = sigmoid(gelu(ea@w1eg+b1eg)@w2eg + b2eg) * V[src]    -> gv (bf16)
// Single edge_attr staging; A-fragments shared by both MLP GEMM1s.
// ---------------------------------------------------------------------------
__global__ __launch_bounds__(256) void k_edge(
    const float* __restrict__ edge_attr, const int* __restrict__ perm,
    const int* __restrict__ srcj, const int* __restrict__ dstj,
    const unsigned short* __restrict__ Qb, const unsigned short* __restrict__ Kb,
    const unsigned short* __restrict__ Vb,
    const unsigned short* __restrict__ w1ea, const float* __restrict__ b1ea,
    const unsigned short* __restrict__ w2ea, const float* __restrict__ b2ea,
    const unsigned short* __restrict__ w1eg, const float* __restrict__ b1eg,
    const unsigned short* __restrict__ w2eg, const float* __restrict__ b2eg,
    float* __restrict__ logit_s, unsigned int* __restrict__ gv)
{
    __shared__ unsigned short ea_lds[256 * 32];   // 16KB; reused as st16 / gv staging
    __shared__ unsigned short hid_lds[256 * 64];  // 32KB; reused by both MLPs
    __shared__ int perm_lds[256];
    __shared__ int src_lds[256];
    float* st16 = (float*)ea_lds;

    const int tid = threadIdx.x;
    const int jBase = blockIdx.x * 256;
    const int lane = tid & 63;
    const int wv = tid >> 6;
    const int wBase = wv * 64;
    const int lm = lane & 15;
    const int kb = lane >> 4;
    const int rowq = kb * 4;

    {
        int j = jBase + tid; if (j >= E) j = E - 1;
        perm_lds[tid] = perm[j];
        src_lds[tid] = srcj[j];
    }
    __syncthreads();

    // stage edge_attr[perm[j]] -> bf16 swizzled LDS
#pragma unroll
    for (int it = 0; it < 8; it++) {
        int idx = it * 256 + tid;
        int el = idx >> 3, c = (idx & 7) * 4;
        int ge = perm_lds[el];
        float4 v = *(const float4*)(edge_attr + (size_t)ge * ED + c);
        int g = ((c >> 3) ^ (el & 3));
        unsigned short* p = &ea_lds[el * 32 + g * 8 + (c & 7)];
        p[0] = f2bf(v.x); p[1] = f2bf(v.y); p[2] = f2bf(v.z); p[3] = f2bf(v.w);
    }
    __syncthreads();

    // shared A-fragments (edge_attr rows) for both GEMM1s
    bf16x8 a1[4];
#pragma unroll
    for (int mt = 0; mt < 4; mt++) {
        int m = wBase + mt * 16 + lm;
        a1[mt] = *(const bf16x8*)&ea_lds[m * 32 + (kb ^ (m & 3)) * 8];
    }

    // ---------------- ea MLP: GEMM1 -> hid_lds ----------------
    {
        f32x4 acc1[4][4];
#pragma unroll
        for (int mt = 0; mt < 4; mt++)
#pragma unroll
            for (int nt = 0; nt < 4; nt++) {
                f32x4 z = {0.f, 0.f, 0.f, 0.f};
                acc1[mt][nt] = __builtin_amdgcn_mfma_f32_16x16x32_bf16(
                    a1[mt], *(const bf16x8*)&w1ea[(nt * 64 + lane) * 8], z, 0, 0, 0);
            }
#pragma unroll
        for (int nt = 0; nt < 4; nt++) {
            float bias = b1ea[nt * 16 + lm];
#pragma unroll
            for (int mt = 0; mt < 4; mt++)
#pragma unroll
                for (int r = 0; r < 4; r++) {
                    int row = wBase + mt * 16 + rowq + r;
                    int col = nt * 16 + lm;
                    int g = (col >> 3) ^ (row & 7);
                    hid_lds[row * 64 + g * 8 + (col & 7)] = f2bf(gelu_f(acc1[mt][nt][r] + bias));
                }
        }
    }

    // ea MLP GEMM2 -> st16 (mlp logits, own-wave rows)
    {
        bf16x8 a2[4][2];
#pragma unroll
        for (int mt = 0; mt < 4; mt++)
#pragma unroll
            for (int ks = 0; ks < 2; ks++) {
                int m = wBase + mt * 16 + lm;
                int g = (ks * 4 + kb) ^ (m & 7);
                a2[mt][ks] = *(const bf16x8*)&hid_lds[m * 64 + g * 8];
            }
        float bias = b2ea[lm & 7];
#pragma unroll
        for (int mt = 0; mt < 4; mt++) {
            f32x4 acc = {bias, bias, bias, bias};
            acc = __builtin_amdgcn_mfma_f32_16x16x32_bf16(
                a2[mt][0], *(const bf16x8*)&w2ea[(0 * 64 + lane) * 8], acc, 0, 0, 0);
            acc = __builtin_amdgcn_mfma_f32_16x16x32_bf16(
                a2[mt][1], *(const bf16x8*)&w2ea[(1 * 64 + lane) * 8], acc, 0, 0, 0);
            if (lm < 8) {
#pragma unroll
                for (int r = 0; r < 4; r++)
                    st16[(wBase + mt * 16 + rowq + r) * 16 + lm] = acc[r];
            }
        }
    }

    // QK epilogue (same-wave st16 rows; no barrier needed)
    {
        int j = jBase + tid;
        if (j < E) {
            int src = src_lds[tid], dst = dstj[j];
            const uint4* qp = (const uint4*)(Qb + (size_t)dst * HID);
            const uint4* kp = (const uint4*)(Kb + (size_t)src * HID);
            float lg[8];
#pragma unroll
            for (int h = 0; h < 8; h++) {
                float dot = 0.f;
#pragma unroll
                for (int t = 0; t < 2; t++) {
                    uint4 q = qp[h * 2 + t], k4 = kp[h * 2 + t];
                    dot += dot2(q.x, k4.x) + dot2(q.y, k4.y) + dot2(q.z, k4.z) + dot2(q.w, k4.w);
                }
                lg[h] = st16[tid * 16 + h] + 0.25f * dot;
            }
            float4* op = (float4*)(logit_s + (size_t)j * NH);
            op[0] = make_float4(lg[0], lg[1], lg[2], lg[3]);
            op[1] = make_float4(lg[4], lg[5], lg[6], lg[7]);
        }
    }

    // ---------------- eg MLP: GEMM1 (reuse a1) -> hid_lds (overwrite own rows) ----
    {
        f32x4 acc1[4][4];
#pragma unroll
        for (int mt = 0; mt < 4; mt++)
#pragma unroll
            for (int nt = 0; nt < 4; nt++) {
                f32x4 z = {0.f, 0.f, 0.f, 0.f};
                acc1[mt][nt] = __builtin_amdgcn_mfma_f32_16x16x32_bf16(
                    a1[mt], *(const bf16x8*)&w1eg[(nt * 64 + lane) * 8], z, 0, 0, 0);
            }
#pragma unroll
        for (int nt = 0; nt < 4; nt++) {
            float bias = b1eg[nt * 16 + lm];
#pragma unroll
            for (int mt = 0; mt < 4; mt++)
#pragma unroll
                for (int r = 0; r < 4; r++) {
                    int row = wBase + mt * 16 + rowq + r;
                    int col = nt * 16 + lm;
                    int g = (col >> 3) ^ (row & 7);
                    hid_lds[row * 64 + g * 8 + (col & 7)] = f2bf(gelu_f(acc1[mt][nt][r] + bias));
                }
        }
    }

    bf16x8 a2[4][2];
#pragma unroll
    for (int mt = 0; mt < 4; mt++)
#pragma unroll
        for (int ks = 0; ks < 2; ks++) {
            int m = wBase + mt * 16 + lm;
            int g = (ks * 4 + kb) ^ (m & 7);
            a2[mt][ks] = *(const bf16x8*)&hid_lds[m * 64 + g * 8];
        }

    // eg GEMM2 in 4 chunks of 32 cols; epilogue sigmoid * V[src] -> gv bf16
#pragma unroll 1
    for (int ch = 0; ch < 4; ch++) {
        const int cc = ch * 32;
        f32x4 acc[4][2];
#pragma unroll
        for (int nt = 0; nt < 2; nt++) {
            float bias = b2eg[cc + nt * 16 + lm];
            const bf16x8 bf0 = *(const bf16x8*)&w2eg[(((ch * 2 + nt) * 2 + 0) * 64 + lane) * 8];
            const bf16x8 bf1 = *(const bf16x8*)&w2eg[(((ch * 2 + nt) * 2 + 1) * 64 + lane) * 8];
#pragma unroll
            for (int mt = 0; mt < 4; mt++) {
                f32x4 c = {bias, bias, bias, bias};
                c = __builtin_amdgcn_mfma_f32_16x16x32_bf16(a2[mt][0], bf0, c, 0, 0, 0);
                c = __builtin_amdgcn_mfma_f32_16x16x32_bf16(a2[mt][1], bf1, c, 0, 0, 0);
                acc[mt][nt] = c;
            }
        }
        __syncthreads();   // waves done with ea_lds (QK epilogue / prev chunk coop reads)
#pragma unroll
        for (int nt = 0; nt < 2; nt++) {
#pragma unroll
            for (int mt = 0; mt < 4; mt++)
#pragma unroll
                for (int r = 0; r < 4; r++) {
                    int em = wBase + mt * 16 + rowq + r;
                    int src = src_lds[em];
                    float vval = __uint_as_float(
                        ((unsigned int)Vb[(size_t)src * HID + cc + nt * 16 + lm]) << 16);
                    float w = sigm_f(acc[mt][nt][r]) * vval;
                    int cl = nt * 16 + lm;
                    int g = (cl >> 3) ^ ((em ^ (em >> 2)) & 3);   // conflict-free across kb
                    ea_lds[em * 32 + g * 8 + (cl & 7)] = f2bf(w);
                }
        }
        __syncthreads();
#pragma unroll
        for (int it = 0; it < 4; it++) {
            int idx = it * 256 + tid;
            int el = idx >> 2, q = idx & 3;
            if (jBase + el < E) {
                int g = q ^ ((el ^ (el >> 2)) & 3);
                uint4 u = *(const uint4*)&ea_lds[el * 32 + g * 8];
                *(uint4*)(gv + (size_t)(jBase + el) * 64 + ch * 16 + q * 4) = u;
            }
        }
    }
}

// ---------------------------------------------------------------------------
// Segment softmax; overwrites logit_s with final attention weights.
// ---------------------------------------------------------------------------
__global__ __launch_bounds__(256) void k_softmax_s(
    const int* __restrict__ starts, float* __restrict__ logit_s)
{
    int i = blockIdx.x * 256 + threadIdx.x;
    if (i >= N * NH) return;
    int dst = i >> 3, h = i & 7;
    int s0 = starts[dst], s1 = starts[dst + 1];
    float m = 0.f;
    for (int j = s0; j < s1; j++)
        m = fmaxf(m, logit_s[(size_t)j * NH + h]);
    float s = 0.f;
    for (int j = s0; j < s1; j++)
        s += __expf(logit_s[(size_t)j * NH + h] - m);
    float rs = 1.f / (s + 1e-10f);
    for (int j = s0; j < s1; j++) {
        size_t idx = (size_t)j * NH + h;
        logit_s[idx] = __expf(logit_s[idx] - m) * rs;
    }
}

// ---------------------------------------------------------------------------
// Streaming attn * gv segment-sum (sorted order). One wave per dst.
// gv uint j*64+lane holds cols {2*lane, 2*lane+1}; head = lane>>3.
// ---------------------------------------------------------------------------
__global__ __launch_bounds__(256) void k_agg2(
    const int* __restrict__ starts, const unsigned int* __restrict__ gv,
    const float* __restrict__ attn_s, float* __restrict__ agg)
{
    int wave = threadIdx.x >> 6, lane = threadIdx.x & 63;
    int dst = blockIdx.x * 4 + wave;
    if (dst >= N) return;
    int s0 = starts[dst], s1 = starts[dst + 1];
    int head = lane >> 3;
    float ax = 0.f, ay = 0.f;
    for (int j = s0; j < s1; j++) {
        float a = attn_s[(size_t)j * NH + head];
        unsigned int u = gv[(size_t)j * 64 + lane];
        ax += a * __uint_as_float(u << 16);
        ay += a * __uint_as_float(u & 0xffff0000u);
    }
    float2* o = (float2*)(agg + (size_t)dst * HID + lane * 2);
    *o = make_float2(ax, ay);
}

// ---------------------------------------------------------------------------
// Node epilogue via MFMA.
// ---------------------------------------------------------------------------
__global__ __launch_bounds__(256) void k_node_out_mfma(
    const float* __restrict__ x, const float* __restrict__ gamma, const float* __restrict__ beta,
    const unsigned short* __restrict__ wo_f, const float* __restrict__ bo,
    const float* __restrict__ g2, const float* __restrict__ b2,
    const unsigned short* __restrict__ fw1_f, const float* __restrict__ fb1,
    const unsigned short* __restrict__ fw2_f, const float* __restrict__ fb2,
    const float* __restrict__ agg, float* __restrict__ out)
{
    __shared__ unsigned short a_lds[64 * 128];
    __shared__ unsigned short f1_lds[64 * 256];
    const int tid = threadIdx.x;
    const int nodeBase = blockIdx.x * 64;

    {
        int nl = tid >> 2, q = tid & 3;
        int gn = nodeBase + nl; if (gn >= N) gn = N - 1;
        const float4* ap = (const float4*)(agg + (size_t)gn * HID + q * 32);
#pragma unroll
        for (int j = 0; j < 4; j++) {
            float4 t0 = ap[2 * j], t1 = ap[2 * j + 1];
            union { unsigned short u[8]; uint4 v4; } o;
            o.u[0] = f2bf(t0.x); o.u[1] = f2bf(t0.y); o.u[2] = f2bf(t0.z); o.u[3] = f2bf(t0.w);
            o.u[4] = f2bf(t1.x); o.u[5] = f2bf(t1.y); o.u[6] = f2bf(t1.z); o.u[7] = f2bf(t1.w);
            int phys = (q * 4 + j) ^ (nl & 15);
            *(uint4*)&a_lds[nl * 128 + phys * 8] = o.v4;
        }
    }
    __syncthreads();

    const int lane = tid & 63, w = tid >> 6, lm = lane & 15, kb = lane >> 4;
    const int rowLoc = w * 16;

    f32x4 xo[8];
    {
        bf16x8 af[4];
#pragma unroll
        for (int ks = 0; ks < 4; ks++)
            af[ks] = *(const bf16x8*)&a_lds[(rowLoc + lm) * 128 + ((ks * 4 + kb) ^ lm) * 8];
#pragma unroll
        for (int nt = 0; nt < 8; nt++) {
            f32x4 c = {0.f, 0.f, 0.f, 0.f};
#pragma unroll
            for (int ks = 0; ks < 4; ks++)
                c = __builtin_amdgcn_mfma_f32_16x16x32_bf16(
                        af[ks], *(const bf16x8*)&wo_f[((size_t)(nt * 4 + ks) * 64 + lane) * 8],
                        c, 0, 0, 0);
            xo[nt] = c;
        }
    }

    float x1v[8][4];
#pragma unroll
    for (int nt = 0; nt < 8; nt++) {
        int col = nt * 16 + lm;
        float boc = bo[col];
#pragma unroll
        for (int r = 0; r < 4; r++) {
            int node = nodeBase + rowLoc + kb * 4 + r; if (node >= N) node = N - 1;
            size_t idx = (size_t)node * HID + col;
            x1v[nt][r] = x[idx] + gamma[idx] * (xo[nt][r] + boc) + beta[idx];
        }
    }

    float s4[4] = {0,0,0,0}, q4[4] = {0,0,0,0};
#pragma unroll
    for (int nt = 0; nt < 8; nt++)
#pragma unroll
        for (int r = 0; r < 4; r++) { s4[r] += x1v[nt][r]; q4[r] += x1v[nt][r] * x1v[nt][r]; }
#pragma unroll
    for (int m = 1; m < 16; m <<= 1)
#pragma unroll
        for (int r = 0; r < 4; r++) { s4[r] += __shfl_xor(s4[r], m); q4[r] += __shfl_xor(q4[r], m); }
    float mu4[4], ri4[4];
#pragma unroll
    for (int r = 0; r < 4; r++) {
        float mu = s4[r] * (1.f / HID);
        mu4[r] = mu;
        ri4[r] = rsqrtf(q4[r] * (1.f / HID) - mu * mu + 1e-5f);
    }

#pragma unroll
    for (int nt = 0; nt < 8; nt++) {
        int col = nt * 16 + lm;
        float g2c = g2[col], b2c = b2[col];
#pragma unroll
        for (int r = 0; r < 4; r++) {
            float xn = (x1v[nt][r] - mu4[r]) * ri4[r] * g2c + b2c;
            int row = rowLoc + kb * 4 + r;
            int g = col >> 3;
            a_lds[row * 128 + (g ^ (row & 15)) * 8 + (col & 7)] = f2bf(xn);
        }
    }
    __syncthreads();

    {
        bf16x8 af[4];
#pragma unroll
        for (int ks = 0; ks < 4; ks++)
            af[ks] = *(const bf16x8*)&a_lds[(rowLoc + lm) * 128 + ((ks * 4 + kb) ^ lm) * 8];
#pragma unroll
        for (int nt = 0; nt < 16; nt++) {
            f32x4 c = {0.f, 0.f, 0.f, 0.f};
#pragma unroll
            for (int ks = 0; ks < 4; ks++)
                c = __builtin_amdgcn_mfma_f32_16x16x32_bf16(
                        af[ks], *(const bf16x8*)&fw1_f[((size_t)(nt * 4 + ks) * 64 + lane) * 8],
                        c, 0, 0, 0);
            int col = nt * 16 + lm;
            float fbc = fb1[col];
#pragma unroll
            for (int r = 0; r < 4; r++) {
                int row = rowLoc + kb * 4 + r;
                int g = col >> 3;
                int phys = (g & 16) | ((g ^ (row & 15)) & 15);
                f1_lds[row * 256 + phys * 8 + (col & 7)] = f2bf(gelu_f(c[r] + fbc));
            }
        }
    }
    __syncthreads();

    {
        bf16x8 af[8];
#pragma unroll
        for (int ks = 0; ks < 8; ks++) {
            int g = ks * 4 + kb;
            int phys = (g & 16) | ((g ^ lm) & 15);
            af[ks] = *(const bf16x8*)&f1_lds[(rowLoc + lm) * 256 + phys * 8];
        }
#pragma unroll
        for (int nt = 0; nt < 8; nt++) {
            f32x4 c = {0.f, 0.f, 0.f, 0.f};
#pragma unroll
            for (int ks = 0; ks < 8; ks++)
                c = __builtin_amdgcn_mfma_f32_16x16x32_bf16(
                        af[ks], *(const bf16x8*)&fw2_f[((size_t)(nt * 8 + ks) * 64 + lane) * 8],
                        c, 0, 0, 0);
            int col = nt * 16 + lm;
            float fbc = fb2[col];
#pragma unroll
            for (int r = 0; r < 4; r++) {
                int node = nodeBase + rowLoc + kb * 4 + r;
                if (node < N) out[(size_t)node * HID + col] = x1v[nt][r] + c[r] + fbc;
            }
        }
    }
}

// ---------------------------------------------------------------------------
extern "C" void kernel_launch(void* const* d_in, const int* in_sizes, int n_in,
                              void* d_out, int out_size, void* d_ws, size_t ws_size,
                              hipStream_t stream)
{
    const float* x         = (const float*)d_in[0];
    const float* edge_attr = (const float*)d_in[1];
    const float* gamma     = (const float*)d_in[2];
    const float* beta      = (const float*)d_in[3];
    const float* Wq        = (const float*)d_in[4];
    const float* Wk        = (const float*)d_in[5];
    const float* Wv        = (const float*)d_in[6];
    const float* Wo        = (const float*)d_in[7];
    const float* bo        = (const float*)d_in[8];
    const float* ea_w1     = (const float*)d_in[9];
    const float* ea_b1     = (const float*)d_in[10];
    const float* ea_w2     = (const float*)d_in[11];
    const float* ea_b2     = (const float*)d_in[12];
    const float* eg_w1     = (const float*)d_in[13];
    const float* eg_b1     = (const float*)d_in[14];
    const float* eg_w2     = (const float*)d_in[15];
    const float* eg_b2     = (const float*)d_in[16];
    const float* ln1_g     = (const float*)d_in[17];
    const float* ln1_b     = (const float*)d_in[18];
    const float* ln2_g     = (const float*)d_in[19];
    const float* ln2_b     = (const float*)d_in[20];
    const float* fw1       = (const float*)d_in[21];
    const float* fb1       = (const float*)d_in[22];
    const float* fw2       = (const float*)d_in[23];
    const float* fb2       = (const float*)d_in[24];
    const int*   ei        = (const int*)d_in[25];

    char* wsb = (char*)d_ws;
    size_t off = 0;
    auto alloc = [&](size_t bytes) { void* p = wsb + off; off += (bytes + 255) & ~(size_t)255; return p; };

    unsigned short* Qb = (unsigned short*)alloc((size_t)N * HID * 2);
    unsigned short* Kb = (unsigned short*)alloc((size_t)N * HID * 2);
    unsigned short* Vb = (unsigned short*)alloc((size_t)N * HID * 2);
    float* logit_s = (float*)alloc((size_t)E * NH * 4);
    float* aggb    = (float*)alloc((size_t)N * HID * 4);
    int*   cnt     = (int*)alloc((size_t)N * 4);
    int*   starts  = (int*)alloc((size_t)(N + 1) * 4);
    int*   cursor  = (int*)alloc((size_t)N * 4);
    int*   bsum    = (int*)alloc((size_t)NB * 4);
    int*   boff    = (int*)alloc((size_t)NB * 4);
    int*   perm    = (int*)alloc((size_t)E * 4);
    int*   srcj    = (int*)alloc((size_t)E * 4);
    int*   dstj    = (int*)alloc((size_t)E * 4);
    unsigned int*   gvb   = (unsigned int*)alloc((size_t)E * 64 * 4);
    unsigned short* fragW = (unsigned short*)alloc((size_t)18048 * 8 * 2);
    float* outp = (float*)d_out;

    unsigned short* wqkv_f = fragW;
    unsigned short* wo_f   = fragW + (size_t)6144  * 8;
    unsigned short* fw1_f  = fragW + (size_t)8192  * 8;
    unsigned short* fw2_f  = fragW + (size_t)12288 * 8;
    unsigned short* w1ea_f = fragW + (size_t)16384 * 8;
    unsigned short* w2ea_f = fragW + (size_t)16640 * 8;
    unsigned short* w1eg_f = fragW + (size_t)16768 * 8;
    unsigned short* w2eg_f = fragW + (size_t)17024 * 8;

    hipMemsetAsync(cnt, 0, (size_t)N * sizeof(int), stream);

    const int EB = (E + 255) / 256;
    const int NBLK = (N + 63) / 64;
    k_cvt<<<(18048 + 255) / 256, 256, 0, stream>>>(Wq, Wk, Wv, Wo, fw1, fw2,
                                                   ea_w1, ea_w2, eg_w1, eg_w2, fragW);
    k_ln_qkv_mfma<<<NBLK, 256, 0, stream>>>(x, ln1_g, ln1_b, wqkv_f, Qb, Kb, Vb);
    k_hist<<<EB, 256, 0, stream>>>(ei, cnt);
    k_bsum<<<NB, 256, 0, stream>>>(cnt, bsum);
    k_scan_b<<<1, 256, 0, stream>>>(bsum, boff);
    k_scan_final<<<NB, 256, 0, stream>>>(cnt, boff, starts, cursor);
    k_scatter<<<EB, 256, 0, stream>>>(ei, cursor, perm, srcj, dstj);
    k_edge<<<EB, 256, 0, stream>>>(edge_attr, perm, srcj, dstj, Qb, Kb, Vb,
                                   w1ea_f, ea_b1, w2ea_f, ea_b2,
                                   w1eg_f, eg_b1, w2eg_f, eg_b2,
                                   logit_s, gvb);
    k_softmax_s<<<(N * NH + 255) / 256, 256, 0, stream>>>(starts, logit_s);
    k_agg2<<<(N + 3) / 4, 256, 0, stream>>>(starts, gvb, logit_s, aggb);
    k_node_out_mfma<<<NBLK, 256, 0, stream>>>(x, gamma, beta, wo_f, bo, ln2_g, ln2_b,
                                              fw1_f, fb1, fw2_f, fb2, aggb, outp);
}